// Round 2
// baseline (262.077 us; speedup 1.0000x reference)
//
#include <hip/hip_runtime.h>

// DiscreteKeyValueBottleneck on MI355X (gfx950)
// B=4 T=1024 H=12 C=4096 DK=DV=64, N=B*T=4096, DIM=768
//
// Round 8: np_recheck was the pole (93us, VALUBusy 10.9%, latency-bound:
// 1 block/entry x 16 serial iterations). Recheck redesigned:
//  * np_part: each flagged entry split into 4 parts of 1024 codes; work
//    items (entry,part) grid-strided over 4096 blocks -> serial depth 4,
//    4x block parallelism. Numpy-bit-exact d2 per code unchanged.
//  * parts merge via packed 64-bit atomicMin: key = order-flipped fp32
//    d2 bits (hi) | code (lo) => (min d2, first index) == jnp.argmin.
//  * np_final gathers values for flagged entries.
// prep_ke / dkvb_pass1 / merge logic byte-identical to round 7.

#define HEADS 12
#define CODES 4096
#define DKI   64
#define DVI   64
#define DIMX  768
#define TAUS  5.12e-3f    // 64 * 8e-5 (scores carry the x64 E-scale)
#define WLCAP 32768

typedef short bf16x8 __attribute__((ext_vector_type(8)));
typedef _Float16 f16x8 __attribute__((ext_vector_type(8)));
typedef float f32x16 __attribute__((ext_vector_type(16)));

__device__ __forceinline__ unsigned short f2bf(float f) {   // RNE
    unsigned int u = __float_as_uint(f);
    return (unsigned short)((u + 0x7fff + ((u >> 16) & 1)) >> 16);
}
__device__ __forceinline__ float bf2f(unsigned short h) {
    return __uint_as_float(((unsigned int)h) << 16);
}
__device__ __forceinline__ unsigned short f2h(float f) {    // RNE f32->f16
    _Float16 h = (_Float16)f;
    unsigned short u;
    __builtin_memcpy(&u, &h, 2);
    return u;
}
__device__ __forceinline__ float h2f(unsigned short u) {
    _Float16 h;
    __builtin_memcpy(&h, &u, 2);
    return (float)h;
}

__device__ __forceinline__ void async_load16(const void* g, void* l) {
    __builtin_amdgcn_global_load_lds(
        (const __attribute__((address_space(1))) unsigned int*)g,
        (__attribute__((address_space(3))) unsigned int*)l, 16, 0, 0);
}

// ---------------- numpy bit-exact helpers (fp32, contraction OFF) -----------
__device__ __forceinline__ float np_sumsq64(const float* __restrict__ a) {
#pragma clang fp contract(off)
    float r[8];
#pragma unroll
    for (int j = 0; j < 8; ++j) r[j] = a[j] * a[j];
#pragma unroll
    for (int i = 8; i < 64; i += 8)
#pragma unroll
        for (int j = 0; j < 8; ++j) r[j] += a[i + j] * a[i + j];
    return ((r[0] + r[1]) + (r[2] + r[3])) + ((r[4] + r[5]) + (r[6] + r[7]));
}

__device__ __forceinline__ float np_dot64(const float* __restrict__ xx,
                                          const float* __restrict__ ee) {
#pragma clang fp contract(off)
    float S0 = 0.f, S1 = 0.f, S2 = 0.f, S3 = 0.f;
#pragma unroll
    for (int t = 0; t < 64; t += 16) {
        float p[16];
#pragma unroll
        for (int j = 0; j < 16; ++j) p[j] = xx[t + j] * ee[t + j];
        S0 = p[0] + (p[4] + (p[8]  + (p[12] + S0)));
        S1 = p[1] + (p[5] + (p[9]  + (p[13] + S1)));
        S2 = p[2] + (p[6] + (p[10] + (p[14] + S2)));
        S3 = p[3] + (p[7] + (p[11] + (p[15] + S3)));
    }
    return (S0 + S1) + (S2 + S3);
}

// ---- prep: np-exact e2; Eh(fp16,x64)/El(bf16 residual) chunk-piece layout --
// uint4 units: [((pair*64 + gg)*8 + piece)*32 + (c&31)], pair = h*2+half,
// gg = (c&2047)>>5. Per 32-code group: 8 pieces x 32 codes x 16B = 4KB.
__global__ __launch_bounds__(256) void prep_ke(const float* __restrict__ ke,
                                               uint4* __restrict__ EhT,
                                               uint4* __restrict__ ElT,
                                               float* __restrict__ e2np,
                                               unsigned short* __restrict__ m2bf,
                                               int* __restrict__ wl_count) {
    if (blockIdx.x == 0 && threadIdx.x == 0) *wl_count = 0;
    int idx = blockIdx.x * 256 + threadIdx.x;
    if (idx >= HEADS * CODES) return;
    float er[DKI];
    const float4* p4 = reinterpret_cast<const float4*>(ke + (size_t)idx * DKI);
#pragma unroll
    for (int i = 0; i < DKI / 4; ++i) {
        float4 v = p4[i];
        er[i * 4 + 0] = v.x; er[i * 4 + 1] = v.y;
        er[i * 4 + 2] = v.z; er[i * 4 + 3] = v.w;
    }
    float e2 = np_sumsq64(er);
    e2np[idx] = e2;

    int h = idx >> 12, c = idx & 4095;
    int half = c >> 11, cw = c & 2047, gg = cw >> 5, cc = c & 31;
    int pair = h * 2 + half;
    m2bf[pair * 2048 + cw] = f2bf(-32.f * e2);   // 64 * (-e2/2), bf16

    size_t base = ((size_t)(pair * 64 + gg) * 8) * 32 + cc;
#pragma unroll
    for (int p = 0; p < 8; ++p) {
        unsigned int hb[8], lb[8];
#pragma unroll
        for (int j = 0; j < 8; ++j) {
            float fs = er[p * 8 + j] * 64.f;      // exact (pow2 scale)
            unsigned short hh = f2h(fs);
            hb[j] = hh;
            float el = fs - h2f(hh);              // exact residual
            lb[j] = f2bf(el);
        }
        uint4 hv, lv;
        hv.x = hb[0] | (hb[1] << 16); hv.y = hb[2] | (hb[3] << 16);
        hv.z = hb[4] | (hb[5] << 16); hv.w = hb[6] | (hb[7] << 16);
        lv.x = lb[0] | (lb[1] << 16); lv.y = lb[2] | (lb[3] << 16);
        lv.z = lb[4] | (lb[5] << 16); lv.w = lb[6] | (lb[7] << 16);
        EhT[base + p * 32] = hv;
        ElT[base + p * 32] = lv;
    }
}

// ---- pass 1: fp16+bf16 2-product MFMA, counted-vmcnt 3-buffer ring ---------
// grid 768 = 24 pairs x 32 q-blocks; pair = b%24 (24%8==0 => XCD-pinned).
// Block: 4 waves, 128 queries, ONE code half (2048 codes, 32x 64-code chunks).
// Wave w stages matrix (w&1) of group (w>>1) each chunk; all consume all.
__global__ __launch_bounds__(256, 3) void dkvb_pass1(
        const float* __restrict__ x,
        const char* __restrict__ EhT,
        const char* __restrict__ ElT,
        const unsigned short* __restrict__ m2bf,
        float* __restrict__ wsv, float* __restrict__ wsv2,
        int* __restrict__ wsi) {
    __shared__ __align__(16) char ldsbuf[3][16384];   // 64 codes x (Eh|El) x 2 grp
    __shared__ __align__(16) unsigned short m2s[2048];

    const int tid  = threadIdx.x;
    const int pr   = blockIdx.x % 24;        // pair = h*2 + half
    const int qb   = blockIdx.x / 24;
    const int h    = pr >> 1;
    const int w    = tid >> 6;
    const int lane = tid & 63;
    const int col  = lane & 31;              // B col (code) / A row (query)
    const int kh   = lane >> 5;              // k-half within K=16 step
    const int q0   = qb * 128;

    // ---- A fragments: query m = q0 + w*32 + col; step t: k = t*16 + kh*8 + j
    const float* xrow = x + (size_t)(q0 + w * 32 + col) * DIMX + h * DKI;
    f16x8 ah[4]; bf16x8 ab[4];
#pragma unroll
    for (int t = 0; t < 4; ++t) {
        const float* p = xrow + t * 16 + kh * 8;
        float4 v0 = *reinterpret_cast<const float4*>(p);
        float4 v1 = *reinterpret_cast<const float4*>(p + 4);
        float f[8] = {v0.x, v0.y, v0.z, v0.w, v1.x, v1.y, v1.z, v1.w};
#pragma unroll
        for (int j = 0; j < 8; ++j) {
            ah[t][j] = (_Float16)f[j];
            ab[t][j] = (short)f2bf(f[j]);
        }
    }

    // ---- stage m2 (bf16, x64 scale) for this half into LDS ----------------
    ((uint4*)m2s)[tid] = ((const uint4*)(m2bf + pr * 2048))[tid];
    asm volatile("s_waitcnt lgkmcnt(0)" ::: "memory");

    // ---- staging role + prologue (chunks 0,1) -----------------------------
    const int g   = w >> 1;
    const int mat = w & 1;
    const char* gsrc = (mat ? ElT : EhT)
                     + ((size_t)(pr * 64 + g)) * 4096 + (size_t)lane * 16;
    const unsigned ldso = (unsigned)(g * 2 + mat) * 4096u;

    char* bA = &ldsbuf[0][0];
    char* bB = &ldsbuf[1][0];
    char* bC = &ldsbuf[2][0];

    auto STAGE = [&](const char* gp, char* lp) {
        async_load16(gp,        lp);
        async_load16(gp + 1024, lp + 1024);
        async_load16(gp + 2048, lp + 2048);
        async_load16(gp + 3072, lp + 3072);
    };
    STAGE(gsrc,        bA + ldso);
    STAGE(gsrc + 8192, bB + ldso);

    float bv[16], bv2[16];
#pragma unroll
    for (int r = 0; r < 16; ++r) { bv[r] = -1e30f; bv2[r] = -1e30f; }

    const int foff = (kh * 32 + col) * 16;   // + t*1024 (piece 2t+kh)

#pragma unroll 1
    for (int i = 0; i < 32; ++i) {
        // counted prefetch: chunks i, i+1 in flight (4 loads each per wave)
        if (i < 31) { asm volatile("s_waitcnt vmcnt(4)" ::: "memory"); }
        else        { asm volatile("s_waitcnt vmcnt(0)" ::: "memory"); }
        __builtin_amdgcn_sched_barrier(0);
        __builtin_amdgcn_s_barrier();        // chunk i valid for all waves
        __builtin_amdgcn_sched_barrier(0);
        if (i + 2 < 32) STAGE(gsrc + (size_t)(i + 2) * 8192, bC + ldso);

#pragma unroll
        for (int g2 = 0; g2 < 2; ++g2) {
            const char* Bb = bA + g2 * 8192 + foff;
            f16x8 bh[4]; bf16x8 bl[4];
#pragma unroll
            for (int t = 0; t < 4; ++t) {
                bh[t] = *reinterpret_cast<const f16x8*>(Bb + t * 1024);
                bl[t] = *reinterpret_cast<const bf16x8*>(Bb + 4096 + t * 1024);
            }
            float m2v = bf2f(m2s[(2 * i + g2) * 32 + col]);
            f32x16 acc;
#pragma unroll
            for (int r = 0; r < 16; ++r) acc[r] = m2v;

            acc = __builtin_amdgcn_mfma_f32_32x32x16_f16 (ah[0], bh[0], acc, 0, 0, 0);
            acc = __builtin_amdgcn_mfma_f32_32x32x16_f16 (ah[1], bh[1], acc, 0, 0, 0);
            acc = __builtin_amdgcn_mfma_f32_32x32x16_f16 (ah[2], bh[2], acc, 0, 0, 0);
            acc = __builtin_amdgcn_mfma_f32_32x32x16_f16 (ah[3], bh[3], acc, 0, 0, 0);
            acc = __builtin_amdgcn_mfma_f32_32x32x16_bf16(ab[0], bl[0], acc, 0, 0, 0);
            acc = __builtin_amdgcn_mfma_f32_32x32x16_bf16(ab[1], bl[1], acc, 0, 0, 0);
            acc = __builtin_amdgcn_mfma_f32_32x32x16_bf16(ab[2], bl[2], acc, 0, 0, 0);
            acc = __builtin_amdgcn_mfma_f32_32x32x16_bf16(ab[3], bl[3], acc, 0, 0, 0);

            // top-2, index packed into mantissa LSBs: 3 VALU/score
            unsigned enc = (unsigned)(2 * i + g2);   // 6-bit group id
#pragma unroll
            for (int r = 0; r < 16; ++r) {
                float sp = __uint_as_float(
                    (__float_as_uint(acc[r]) & 0xFFFFFFC0u) | enc);
                bv2[r] = __builtin_amdgcn_fmed3f(bv2[r], sp, bv[r]);
                bv[r]  = fmaxf(bv[r], sp);
            }
        }
        char* tsw = bA; bA = bB; bB = bC; bC = tsw;   // rotate ring
    }

    // ---- decode packed index, cross-col top-2 butterfly --------------------
    int bi[16];
#pragma unroll
    for (int r = 0; r < 16; ++r)
        bi[r] = (int)(__float_as_uint(bv[r]) & 63u) * 32 + col;  // within-half c
#pragma unroll
    for (int r = 0; r < 16; ++r) {
#pragma unroll
        for (int m = 1; m <= 16; m <<= 1) {
            float pv1 = __shfl_xor(bv[r],  m, 64);
            float pv2 = __shfl_xor(bv2[r], m, 64);
            int   pi  = __shfl_xor(bi[r],  m, 64);
            bool take = (pv1 > bv[r]) || (pv1 == bv[r] && pi < bi[r]);
            float lo1 = take ? bv[r] : pv1;
            bv2[r] = fmaxf(lo1, fmaxf(bv2[r], pv2));
            bv[r]  = take ? pv1 : bv[r];
            bi[r]  = take ? pi  : bi[r];
        }
    }
    if (col == 0) {                          // lanes 0 and 32
#pragma unroll
        for (int r = 0; r < 16; ++r) {
            int row = (r & 3) + 8 * (r >> 2) + 4 * kh;
            int q = q0 + w * 32 + row;
            size_t o = (size_t)pr * 4096 + q;
            wsv[o]  = bv[r];
            wsv2[o] = bv2[r];
            wsi[o]  = bi[r];
        }
    }
}

// ---- merge halves, margin flag, gather values -> out -----------------------
__global__ __launch_bounds__(256) void merge_out(const float* __restrict__ wsv,
                                                 const float* __restrict__ wsv2,
                                                 const int* __restrict__ wsi,
                                                 const float* __restrict__ values,
                                                 int* __restrict__ wl_count,
                                                 int* __restrict__ wl,
                                                 unsigned long long* __restrict__ res,
                                                 float* __restrict__ out) {
    __shared__ int fin[64];
    const int b = blockIdx.x;
    const int h = b >> 6;
    const int q0 = (b & 63) << 6;
    const int tid = threadIdx.x;
    if (tid < 64) {
        int q = q0 + tid;
        size_t p0 = (size_t)(h * 2) * 4096 + q, p1 = p0 + 4096;
        float a1 = wsv[p0], a2 = wsv2[p0];
        float b1 = wsv[p1], b2 = wsv2[p1];
        bool tb = b1 > a1;                   // tie -> half 0 (smaller c)
        float bvm = tb ? b1 : a1;
        int c = tb ? (2048 + wsi[p1]) : wsi[p0];
        float runner = fmaxf(fmaxf(a2, b2), fminf(a1, b1));
        fin[tid] = c;
        if (bvm - runner < TAUS) {
            int slot = atomicAdd(wl_count, 1);
            if (slot < WLCAP) {
                wl[slot]  = (h << 16) | q;
                res[slot] = ~0ULL;           // init packed-min accumulator
            }
        }
    }
    __syncthreads();
#pragma unroll
    for (int k = 0; k < 4; ++k) {
        int f   = tid + k * 256;
        int row = f >> 4;
        int cl  = (f & 15) << 2;
        int idx = fin[row];
        float4 v = *reinterpret_cast<const float4*>(
            values + (size_t)h * CODES * DVI + (size_t)idx * DVI + cl);
        *reinterpret_cast<float4*>(
            out + (size_t)(q0 + row) * DIMX + h * DVI + cl) = v;
    }
}

// ---- pass 2a: numpy-bit-exact partial re-argmin, 4 parts per entry ---------
// work item = (entry, quarter of codebook); packed 64-bit atomicMin merges:
// key = order-flipped d2 bits (hi) | code (lo) -> (min d2, first index).
__global__ __launch_bounds__(256) void np_part(const float* __restrict__ x,
                                               const float* __restrict__ ke,
                                               const float* __restrict__ e2np,
                                               const int* __restrict__ wl_count,
                                               const int* __restrict__ wl,
                                               unsigned long long* __restrict__ res) {
    __shared__ float xs[DKI];
    const int t = threadIdx.x;
    int cnt = *wl_count;
    if (cnt > WLCAP) cnt = WLCAP;
    const int total = cnt * 4;

    for (int wk = blockIdx.x; wk < total; wk += gridDim.x) {
        __syncthreads();                     // xs reuse across wk iterations
        const int e = wk >> 2, part = wk & 3;
        const int ent = wl[e];
        const int h = ent >> 16, nq = ent & 0xffff;
        if (t < DKI) xs[t] = x[(size_t)nq * DIMX + h * DKI + t];
        __syncthreads();

        float x2 = np_sumsq64(xs);

        unsigned long long best = ~0ULL;
#pragma unroll 1
        for (int it = 0; it < 4; ++it) {
            int c = part * 1024 + it * 256 + t;
            float er[DKI];
            const float4* p = reinterpret_cast<const float4*>(
                ke + ((size_t)h * CODES + c) * DKI);
#pragma unroll
            for (int i = 0; i < DKI / 4; ++i) {
                float4 v = p[i];
                er[i * 4 + 0] = v.x; er[i * 4 + 1] = v.y;
                er[i * 4 + 2] = v.z; er[i * 4 + 3] = v.w;
            }
            float dot = np_dot64(xs, er);
            float d2;
            {
#pragma clang fp contract(off)
                d2 = (x2 - 2.0f * dot) + e2np[h * CODES + c];
            }
            unsigned u = __float_as_uint(d2);
            unsigned key = (u & 0x80000000u) ? ~u : (u | 0x80000000u);
            unsigned long long pk = ((unsigned long long)key << 32) | (unsigned)c;
            best = pk < best ? pk : best;
        }
        // 64-lane min butterfly on packed key
#pragma unroll
        for (int m = 1; m <= 32; m <<= 1) {
            unsigned long long o =
                (unsigned long long)__shfl_xor((long long)best, m, 64);
            best = o < best ? o : best;
        }
        if ((t & 63) == 0) atomicMin(res + e, best);
    }
}

// ---- pass 2b: write recheck winners ----------------------------------------
__global__ __launch_bounds__(256) void np_final(const float* __restrict__ values,
                                                const int* __restrict__ wl_count,
                                                const int* __restrict__ wl,
                                                const unsigned long long* __restrict__ res,
                                                float* __restrict__ out) {
    int cnt = *wl_count;
    if (cnt > WLCAP) cnt = WLCAP;
    const int total = cnt * 16;              // 16 float4 per entry
    for (int f = blockIdx.x * 256 + threadIdx.x; f < total; f += gridDim.x * 256) {
        int e  = f >> 4;
        int cl = (f & 15) << 2;
        int ent = wl[e];
        int h = ent >> 16, nq = ent & 0xffff;
        int c = (int)(res[e] & 0xFFFFFFFFULL);
        float4 v = *reinterpret_cast<const float4*>(
            values + ((size_t)h * CODES + c) * DVI + cl);
        *reinterpret_cast<float4*>(
            out + (size_t)nq * DIMX + h * DVI + cl) = v;
    }
}

extern "C" void kernel_launch(void* const* d_in, const int* in_sizes, int n_in,
                              void* d_out, int out_size, void* d_ws, size_t ws_size,
                              hipStream_t stream) {
    const float* x      = (const float*)d_in[0];
    // d_in[1] = mask (all ones; unused)
    const float* ke     = (const float*)d_in[2];
    const float* values = (const float*)d_in[3];
    // d_in[4] = key_optim (unused)
    float* out = (float*)d_out;

    char* ws = (char*)d_ws;
    float* e2np          = (float*)ws;          ws += (size_t)HEADS * CODES * 4;      // 196608
    unsigned short* m2bf = (unsigned short*)ws; ws += (size_t)HEADS * 2 * 2048 * 2;   // 98304
    float* wsv           = (float*)ws;          ws += (size_t)24 * 4096 * 4;          // 393216
    float* wsv2          = (float*)ws;          ws += (size_t)24 * 4096 * 4;
    int*   wsi           = (int*)ws;            ws += (size_t)24 * 4096 * 4;
    int*   wl_count      = (int*)ws;            ws += 64;
    int*   wl            = (int*)ws;            ws += (size_t)WLCAP * 4;              // 131072
    unsigned long long* res = (unsigned long long*)ws; ws += (size_t)WLCAP * 8;       // 262144
    char*  EhT           = ws;                  ws += (size_t)HEADS * CODES * 128;    // 6291456
    char*  ElT           = ws;

    prep_ke<<<dim3((HEADS * CODES + 255) / 256), dim3(256), 0, stream>>>(
        ke, (uint4*)EhT, (uint4*)ElT, e2np, m2bf, wl_count);
    dkvb_pass1<<<dim3(768), dim3(256), 0, stream>>>(
        x, EhT, ElT, m2bf, wsv, wsv2, wsi);
    merge_out<<<dim3(768), dim3(256), 0, stream>>>(
        wsv, wsv2, wsi, values, wl_count, wl, res, out);
    np_part<<<dim3(4096), dim3(256), 0, stream>>>(
        x, ke, e2np, wl_count, wl, res);
    np_final<<<dim3(1024), dim3(256), 0, stream>>>(
        values, wl_count, wl, res, out);
}

// Round 3
// 251.268 us; speedup vs baseline: 1.0430x; 1.0430x over previous
//
#include <hip/hip_runtime.h>

// DiscreteKeyValueBottleneck on MI355X (gfx950)
// B=4 T=1024 H=12 C=4096 DK=DV=64, N=B*T=4096, DIM=768
//
// Round 9: recheck was L2-BW-bound on cnt x 1MB ke rescans (93us, identical
// across two structures; cnt ~= 3200 at 6.5% flag rate). Redesign:
//  * pass1 tracks TOP-3 per query (one extra fmed3/score; packed-index
//    mantissa trick yields i1,i2,i3). Exact top-3 butterfly merge.
//  * merge_out: if v1-v2 >= TAUS accept; else if v3 < v1-TAUS the true
//    argmin is provably in {i1,i2} (errors <= TAUS/2) -> 2-candidate
//    np-exact check (512B instead of 1MB per flagged query); else (rare
//    near-ties) full np-exact wave scan fallback. np_part/np_final gone.
//  * cand_check: one wave per flagged entry; lanes 0/1 run the np-exact
//    chains for the two candidates; fallback path scans 4096 codes with
//    64 lanes + packed-key min butterfly (jnp.argmin tie-break).
// prep_ke / dkvb_pass1 core / np helpers byte-identical arithmetic.

#define HEADS 12
#define CODES 4096
#define DKI   64
#define DVI   64
#define DIMX  768
#define TAUS  5.12e-3f    // 64 * 8e-5 (scores carry the x64 E-scale)
#define WLCAP 32768

typedef short bf16x8 __attribute__((ext_vector_type(8)));
typedef _Float16 f16x8 __attribute__((ext_vector_type(8)));
typedef float f32x16 __attribute__((ext_vector_type(16)));

__device__ __forceinline__ unsigned short f2bf(float f) {   // RNE
    unsigned int u = __float_as_uint(f);
    return (unsigned short)((u + 0x7fff + ((u >> 16) & 1)) >> 16);
}
__device__ __forceinline__ float bf2f(unsigned short h) {
    return __uint_as_float(((unsigned int)h) << 16);
}
__device__ __forceinline__ unsigned short f2h(float f) {    // RNE f32->f16
    _Float16 h = (_Float16)f;
    unsigned short u;
    __builtin_memcpy(&u, &h, 2);
    return u;
}
__device__ __forceinline__ float h2f(unsigned short u) {
    _Float16 h;
    __builtin_memcpy(&h, &u, 2);
    return (float)h;
}

__device__ __forceinline__ void async_load16(const void* g, void* l) {
    __builtin_amdgcn_global_load_lds(
        (const __attribute__((address_space(1))) unsigned int*)g,
        (__attribute__((address_space(3))) unsigned int*)l, 16, 0, 0);
}

// ---------------- numpy bit-exact helpers (fp32, contraction OFF) -----------
__device__ __forceinline__ float np_sumsq64(const float* __restrict__ a) {
#pragma clang fp contract(off)
    float r[8];
#pragma unroll
    for (int j = 0; j < 8; ++j) r[j] = a[j] * a[j];
#pragma unroll
    for (int i = 8; i < 64; i += 8)
#pragma unroll
        for (int j = 0; j < 8; ++j) r[j] += a[i + j] * a[i + j];
    return ((r[0] + r[1]) + (r[2] + r[3])) + ((r[4] + r[5]) + (r[6] + r[7]));
}

__device__ __forceinline__ float np_dot64(const float* __restrict__ xx,
                                          const float* __restrict__ ee) {
#pragma clang fp contract(off)
    float S0 = 0.f, S1 = 0.f, S2 = 0.f, S3 = 0.f;
#pragma unroll
    for (int t = 0; t < 64; t += 16) {
        float p[16];
#pragma unroll
        for (int j = 0; j < 16; ++j) p[j] = xx[t + j] * ee[t + j];
        S0 = p[0] + (p[4] + (p[8]  + (p[12] + S0)));
        S1 = p[1] + (p[5] + (p[9]  + (p[13] + S1)));
        S2 = p[2] + (p[6] + (p[10] + (p[14] + S2)));
        S3 = p[3] + (p[7] + (p[11] + (p[15] + S3)));
    }
    return (S0 + S1) + (S2 + S3);
}

// ---- prep: np-exact e2; Eh(fp16,x64)/El(bf16 residual) chunk-piece layout --
// uint4 units: [((pair*64 + gg)*8 + piece)*32 + (c&31)], pair = h*2+half,
// gg = (c&2047)>>5. Per 32-code group: 8 pieces x 32 codes x 16B = 4KB.
__global__ __launch_bounds__(256) void prep_ke(const float* __restrict__ ke,
                                               uint4* __restrict__ EhT,
                                               uint4* __restrict__ ElT,
                                               float* __restrict__ e2np,
                                               unsigned short* __restrict__ m2bf,
                                               int* __restrict__ wl_count) {
    if (blockIdx.x == 0 && threadIdx.x == 0) *wl_count = 0;
    int idx = blockIdx.x * 256 + threadIdx.x;
    if (idx >= HEADS * CODES) return;
    float er[DKI];
    const float4* p4 = reinterpret_cast<const float4*>(ke + (size_t)idx * DKI);
#pragma unroll
    for (int i = 0; i < DKI / 4; ++i) {
        float4 v = p4[i];
        er[i * 4 + 0] = v.x; er[i * 4 + 1] = v.y;
        er[i * 4 + 2] = v.z; er[i * 4 + 3] = v.w;
    }
    float e2 = np_sumsq64(er);
    e2np[idx] = e2;

    int h = idx >> 12, c = idx & 4095;
    int half = c >> 11, cw = c & 2047, gg = cw >> 5, cc = c & 31;
    int pair = h * 2 + half;
    m2bf[pair * 2048 + cw] = f2bf(-32.f * e2);   // 64 * (-e2/2), bf16

    size_t base = ((size_t)(pair * 64 + gg) * 8) * 32 + cc;
#pragma unroll
    for (int p = 0; p < 8; ++p) {
        unsigned int hb[8], lb[8];
#pragma unroll
        for (int j = 0; j < 8; ++j) {
            float fs = er[p * 8 + j] * 64.f;      // exact (pow2 scale)
            unsigned short hh = f2h(fs);
            hb[j] = hh;
            float el = fs - h2f(hh);              // exact residual
            lb[j] = f2bf(el);
        }
        uint4 hv, lv;
        hv.x = hb[0] | (hb[1] << 16); hv.y = hb[2] | (hb[3] << 16);
        hv.z = hb[4] | (hb[5] << 16); hv.w = hb[6] | (hb[7] << 16);
        lv.x = lb[0] | (lb[1] << 16); lv.y = lb[2] | (lb[3] << 16);
        lv.z = lb[4] | (lb[5] << 16); lv.w = lb[6] | (lb[7] << 16);
        EhT[base + p * 32] = hv;
        ElT[base + p * 32] = lv;
    }
}

// ---- pass 1: fp16+bf16 2-product MFMA, counted-vmcnt ring, TOP-3 track -----
// grid 768 = 24 pairs x 32 q-blocks; pair = b%24 (24%8==0 => XCD-pinned).
// Block: 4 waves, 128 queries, ONE code half (2048 codes, 32x 64-code chunks).
__global__ __launch_bounds__(256, 3) void dkvb_pass1(
        const float* __restrict__ x,
        const char* __restrict__ EhT,
        const char* __restrict__ ElT,
        const unsigned short* __restrict__ m2bf,
        float* __restrict__ wsv1, float* __restrict__ wsv2,
        float* __restrict__ wsv3,
        int* __restrict__ wsi12, int* __restrict__ wsi3) {
    __shared__ __align__(16) char ldsbuf[3][16384];   // 64 codes x (Eh|El) x 2 grp
    __shared__ __align__(16) unsigned short m2s[2048];

    const int tid  = threadIdx.x;
    const int pr   = blockIdx.x % 24;        // pair = h*2 + half
    const int qb   = blockIdx.x / 24;
    const int h    = pr >> 1;
    const int w    = tid >> 6;
    const int lane = tid & 63;
    const int col  = lane & 31;              // B col (code) / A row (query)
    const int kh   = lane >> 5;              // k-half within K=16 step
    const int q0   = qb * 128;

    // ---- A fragments: query m = q0 + w*32 + col; step t: k = t*16 + kh*8 + j
    const float* xrow = x + (size_t)(q0 + w * 32 + col) * DIMX + h * DKI;
    f16x8 ah[4]; bf16x8 ab[4];
#pragma unroll
    for (int t = 0; t < 4; ++t) {
        const float* p = xrow + t * 16 + kh * 8;
        float4 v0 = *reinterpret_cast<const float4*>(p);
        float4 v1 = *reinterpret_cast<const float4*>(p + 4);
        float f[8] = {v0.x, v0.y, v0.z, v0.w, v1.x, v1.y, v1.z, v1.w};
#pragma unroll
        for (int j = 0; j < 8; ++j) {
            ah[t][j] = (_Float16)f[j];
            ab[t][j] = (short)f2bf(f[j]);
        }
    }

    // ---- stage m2 (bf16, x64 scale) for this half into LDS ----------------
    ((uint4*)m2s)[tid] = ((const uint4*)(m2bf + pr * 2048))[tid];
    asm volatile("s_waitcnt lgkmcnt(0)" ::: "memory");

    // ---- staging role + prologue (chunks 0,1) -----------------------------
    const int g   = w >> 1;
    const int mat = w & 1;
    const char* gsrc = (mat ? ElT : EhT)
                     + ((size_t)(pr * 64 + g)) * 4096 + (size_t)lane * 16;
    const unsigned ldso = (unsigned)(g * 2 + mat) * 4096u;

    char* bA = &ldsbuf[0][0];
    char* bB = &ldsbuf[1][0];
    char* bC = &ldsbuf[2][0];

    auto STAGE = [&](const char* gp, char* lp) {
        async_load16(gp,        lp);
        async_load16(gp + 1024, lp + 1024);
        async_load16(gp + 2048, lp + 2048);
        async_load16(gp + 3072, lp + 3072);
    };
    STAGE(gsrc,        bA + ldso);
    STAGE(gsrc + 8192, bB + ldso);

    float bv[16], bv2[16], bv3[16];
#pragma unroll
    for (int r = 0; r < 16; ++r) { bv[r] = -1e30f; bv2[r] = -1e30f; bv3[r] = -1e30f; }

    const int foff = (kh * 32 + col) * 16;   // + t*1024 (piece 2t+kh)

#pragma unroll 1
    for (int i = 0; i < 32; ++i) {
        // counted prefetch: chunks i, i+1 in flight (4 loads each per wave)
        if (i < 31) { asm volatile("s_waitcnt vmcnt(4)" ::: "memory"); }
        else        { asm volatile("s_waitcnt vmcnt(0)" ::: "memory"); }
        __builtin_amdgcn_sched_barrier(0);
        __builtin_amdgcn_s_barrier();        // chunk i valid for all waves
        __builtin_amdgcn_sched_barrier(0);
        if (i + 2 < 32) STAGE(gsrc + (size_t)(i + 2) * 8192, bC + ldso);

#pragma unroll
        for (int g2 = 0; g2 < 2; ++g2) {
            const char* Bb = bA + g2 * 8192 + foff;
            f16x8 bh[4]; bf16x8 bl[4];
#pragma unroll
            for (int t = 0; t < 4; ++t) {
                bh[t] = *reinterpret_cast<const f16x8*>(Bb + t * 1024);
                bl[t] = *reinterpret_cast<const bf16x8*>(Bb + 4096 + t * 1024);
            }
            float m2v = bf2f(m2s[(2 * i + g2) * 32 + col]);
            f32x16 acc;
#pragma unroll
            for (int r = 0; r < 16; ++r) acc[r] = m2v;

            acc = __builtin_amdgcn_mfma_f32_32x32x16_f16 (ah[0], bh[0], acc, 0, 0, 0);
            acc = __builtin_amdgcn_mfma_f32_32x32x16_f16 (ah[1], bh[1], acc, 0, 0, 0);
            acc = __builtin_amdgcn_mfma_f32_32x32x16_f16 (ah[2], bh[2], acc, 0, 0, 0);
            acc = __builtin_amdgcn_mfma_f32_32x32x16_f16 (ah[3], bh[3], acc, 0, 0, 0);
            acc = __builtin_amdgcn_mfma_f32_32x32x16_bf16(ab[0], bl[0], acc, 0, 0, 0);
            acc = __builtin_amdgcn_mfma_f32_32x32x16_bf16(ab[1], bl[1], acc, 0, 0, 0);
            acc = __builtin_amdgcn_mfma_f32_32x32x16_bf16(ab[2], bl[2], acc, 0, 0, 0);
            acc = __builtin_amdgcn_mfma_f32_32x32x16_bf16(ab[3], bl[3], acc, 0, 0, 0);

            // top-3, index packed into mantissa LSBs: 4 VALU/score
            unsigned enc = (unsigned)(2 * i + g2);   // 6-bit group id
#pragma unroll
            for (int r = 0; r < 16; ++r) {
                float sp = __uint_as_float(
                    (__float_as_uint(acc[r]) & 0xFFFFFFC0u) | enc);
                bv3[r] = __builtin_amdgcn_fmed3f(bv3[r], sp, bv2[r]);  // old v2
                bv2[r] = __builtin_amdgcn_fmed3f(bv2[r], sp, bv[r]);   // old v1
                bv[r]  = fmaxf(bv[r], sp);
            }
        }
        char* tsw = bA; bA = bB; bB = bC; bC = tsw;   // rotate ring
    }

    // ---- decode packed indices, cross-col top-3 butterfly ------------------
    int bi1[16], bi2[16], bi3[16];
#pragma unroll
    for (int r = 0; r < 16; ++r) {
        bi1[r] = (int)(__float_as_uint(bv[r])  & 63u) * 32 + col;
        bi2[r] = (int)(__float_as_uint(bv2[r]) & 63u) * 32 + col;
        bi3[r] = (int)(__float_as_uint(bv3[r]) & 63u) * 32 + col;
    }
    // exact top-3 merge network (value-strict; rank-2/3 value ties are caught
    // later by the v3 >= v1-TAUS fallback, so lane tie-consistency is not
    // required for correctness)
#pragma unroll
    for (int r = 0; r < 16; ++r) {
#pragma unroll
        for (int m = 1; m <= 16; m <<= 1) {
            float p1 = __shfl_xor(bv[r],  m, 64);
            float p2 = __shfl_xor(bv2[r], m, 64);
            float p3 = __shfl_xor(bv3[r], m, 64);
            int   q1 = __shfl_xor(bi1[r], m, 64);
            int   q2 = __shfl_xor(bi2[r], m, 64);
            int   q3 = __shfl_xor(bi3[r], m, 64);
            bool t1 = p1 > bv[r];
            float w1 = t1 ? p1 : bv[r];   int j1 = t1 ? q1 : bi1[r];
            float l1 = t1 ? bv[r] : p1;   int k1 = t1 ? bi1[r] : q1;
            float s2 = t1 ? p2 : bv2[r];  int u2 = t1 ? q2 : bi2[r];
            bool t2 = s2 > l1;
            float w2 = t2 ? s2 : l1;      int j2 = t2 ? u2 : k1;
            float l2 = t2 ? l1 : s2;      int k2 = t2 ? k1 : u2;
            float s3 = t2 ? (t1 ? p3 : bv3[r]) : (t1 ? bv2[r] : p2);
            int   u3 = t2 ? (t1 ? q3 : bi3[r]) : (t1 ? bi2[r] : q2);
            bool t3 = s3 > l2;
            float w3 = t3 ? s3 : l2;      int j3 = t3 ? u3 : k2;
            bv[r] = w1; bi1[r] = j1;
            bv2[r] = w2; bi2[r] = j2;
            bv3[r] = w3; bi3[r] = j3;
        }
    }
    if (col == 0) {                          // lanes 0 and 32
#pragma unroll
        for (int r = 0; r < 16; ++r) {
            int row = (r & 3) + 8 * (r >> 2) + 4 * kh;
            int q = q0 + w * 32 + row;
            size_t o = (size_t)pr * 4096 + q;
            wsv1[o] = bv[r];
            wsv2[o] = bv2[r];
            wsv3[o] = bv3[r];
            wsi12[o] = bi1[r] | (bi2[r] << 16);
            wsi3[o]  = bi3[r];
        }
    }
}

// ---- merge halves, margin flag (2-cand or fallback), gather values ---------
__global__ __launch_bounds__(256) void merge_out(const float* __restrict__ wsv1,
                                                 const float* __restrict__ wsv2,
                                                 const float* __restrict__ wsv3,
                                                 const int* __restrict__ wsi12,
                                                 const int* __restrict__ wsi3,
                                                 const float* __restrict__ values,
                                                 int* __restrict__ wl_count,
                                                 int* __restrict__ wl,
                                                 int* __restrict__ wlc,
                                                 float* __restrict__ out) {
    __shared__ int fin[64];
    const int b = blockIdx.x;
    const int h = b >> 6;
    const int q0 = (b & 63) << 6;
    const int tid = threadIdx.x;
    if (tid < 64) {
        int q = q0 + tid;
        size_t p0 = (size_t)(h * 2) * 4096 + q, p1 = p0 + 4096;
        float a1 = wsv1[p0], a2 = wsv2[p0], a3 = wsv3[p0];
        int ai = wsi12[p0];
        int ia1 = ai & 0xffff, ia2 = (ai >> 16) & 0xffff, ia3 = wsi3[p0];
        float c1 = wsv1[p1], c2 = wsv2[p1], c3 = wsv3[p1];
        int ci = wsi12[p1];
        int ib1 = (ci & 0xffff) + 2048, ib2 = ((ci >> 16) & 0xffff) + 2048,
            ib3 = wsi3[p1] + 2048;
        // exact top-3 merge of two sorted triples (tie at rank1 -> half 0)
        bool t1 = c1 > a1;
        float v1 = t1 ? c1 : a1;  int i1 = t1 ? ib1 : ia1;
        float l1 = t1 ? a1 : c1;  int k1 = t1 ? ia1 : ib1;
        float s2 = t1 ? c2 : a2;  int u2 = t1 ? ib2 : ia2;
        bool t2 = s2 > l1;
        float v2 = t2 ? s2 : l1;  int i2 = t2 ? u2 : k1;
        float l2 = t2 ? l1 : s2;
        float s3 = t2 ? (t1 ? c3 : a3) : (t1 ? a2 : c2);
        bool t3 = s3 > l2;
        float v3 = t3 ? s3 : l2;
        fin[tid] = i1;
        if (v1 - v2 < TAUS) {
            int slot = atomicAdd(wl_count, 1);
            if (slot < WLCAP) {
                wl[slot]  = (h << 16) | q;
                // provable candidate set {i1,i2} unless v3 within margin too
                wlc[slot] = (v1 - v3 < TAUS) ? -1 : ((i1 << 16) | i2);
            }
        }
    }
    __syncthreads();
#pragma unroll
    for (int k = 0; k < 4; ++k) {
        int f   = tid + k * 256;
        int row = f >> 4;
        int cl  = (f & 15) << 2;
        int idx = fin[row];
        float4 v = *reinterpret_cast<const float4*>(
            values + (size_t)h * CODES * DVI + (size_t)idx * DVI + cl);
        *reinterpret_cast<float4*>(
            out + (size_t)(q0 + row) * DIMX + h * DVI + cl) = v;
    }
}

// ---- pass 2: np-exact candidate check, one wave per flagged entry ----------
// wlc >= 0: two candidates (lanes 0,1 run the np chains in lockstep).
// wlc == -1: rare near-tie fallback -> full 4096-code np scan by the wave,
// packed-key min butterfly reproduces jnp.argmin first-index tie-break.
__global__ __launch_bounds__(256) void cand_check(const float* __restrict__ x,
                                                  const float* __restrict__ ke,
                                                  const float* __restrict__ e2np,
                                                  const float* __restrict__ values,
                                                  const int* __restrict__ wl_count,
                                                  const int* __restrict__ wl,
                                                  const int* __restrict__ wlc,
                                                  float* __restrict__ out) {
    __shared__ float xs[4][DKI];
    const int t = threadIdx.x, w = t >> 6, lane = t & 63;
    int cnt = *wl_count;
    if (cnt > WLCAP) cnt = WLCAP;

    for (int e = blockIdx.x * 4 + w; e < cnt; e += gridDim.x * 4) {
        int ent = wl[e];
        int h = ent >> 16, nq = ent & 0xffff;
        int cp = wlc[e];
        if (lane < 16) {
            float4 v = *reinterpret_cast<const float4*>(
                x + (size_t)nq * DIMX + h * DKI + lane * 4);
            *reinterpret_cast<float4*>(&xs[w][lane * 4]) = v;
        }
        asm volatile("s_waitcnt lgkmcnt(0)" ::: "memory");
        __builtin_amdgcn_sched_barrier(0);

        int win;
        if (cp >= 0) {
            int i1 = (cp >> 16) & 0xffff, i2 = cp & 0xffff;
            float d2 = 0.f;
            if (lane < 2) {
                int myc = lane ? i2 : i1;
                float er[DKI];
                const float4* p = reinterpret_cast<const float4*>(
                    ke + ((size_t)h * CODES + myc) * DKI);
#pragma unroll
                for (int i = 0; i < DKI / 4; ++i) {
                    float4 v = p[i];
                    er[i * 4 + 0] = v.x; er[i * 4 + 1] = v.y;
                    er[i * 4 + 2] = v.z; er[i * 4 + 3] = v.w;
                }
                float x2 = np_sumsq64(xs[w]);
                float dot = np_dot64(xs[w], er);
                {
#pragma clang fp contract(off)
                    d2 = (x2 - 2.0f * dot) + e2np[h * CODES + myc];
                }
            }
            float dA = __shfl(d2, 0, 64);
            float dB = __shfl(d2, 1, 64);
            win = (dB < dA || (dB == dA && i2 < i1)) ? i2 : i1;
        } else {
            float x2 = np_sumsq64(xs[w]);
            unsigned long long best = ~0ULL;
#pragma unroll 1
            for (int it = 0; it < 64; ++it) {
                int c = it * 64 + lane;
                float er[DKI];
                const float4* p = reinterpret_cast<const float4*>(
                    ke + ((size_t)h * CODES + c) * DKI);
#pragma unroll
                for (int i = 0; i < DKI / 4; ++i) {
                    float4 v = p[i];
                    er[i * 4 + 0] = v.x; er[i * 4 + 1] = v.y;
                    er[i * 4 + 2] = v.z; er[i * 4 + 3] = v.w;
                }
                float dot = np_dot64(xs[w], er);
                float d2;
                {
#pragma clang fp contract(off)
                    d2 = (x2 - 2.0f * dot) + e2np[h * CODES + c];
                }
                unsigned u = __float_as_uint(d2);
                unsigned key = (u & 0x80000000u) ? ~u : (u | 0x80000000u);
                unsigned long long pk =
                    ((unsigned long long)key << 32) | (unsigned)c;
                best = pk < best ? pk : best;
            }
#pragma unroll
            for (int m = 1; m <= 32; m <<= 1) {
                unsigned long long o =
                    (unsigned long long)__shfl_xor((long long)best, m, 64);
                best = o < best ? o : best;
            }
            win = (int)(best & 0xFFFFFFFFULL);
        }
        if (lane < 16) {
            float4 v = *reinterpret_cast<const float4*>(
                values + ((size_t)h * CODES + win) * DVI + lane * 4);
            *reinterpret_cast<float4*>(
                out + (size_t)nq * DIMX + h * DVI + lane * 4) = v;
        }
    }
}

extern "C" void kernel_launch(void* const* d_in, const int* in_sizes, int n_in,
                              void* d_out, int out_size, void* d_ws, size_t ws_size,
                              hipStream_t stream) {
    const float* x      = (const float*)d_in[0];
    // d_in[1] = mask (all ones; unused)
    const float* ke     = (const float*)d_in[2];
    const float* values = (const float*)d_in[3];
    // d_in[4] = key_optim (unused)
    float* out = (float*)d_out;

    char* ws = (char*)d_ws;
    float* e2np          = (float*)ws;          ws += (size_t)HEADS * CODES * 4;      // 196608
    unsigned short* m2bf = (unsigned short*)ws; ws += (size_t)HEADS * 2 * 2048 * 2;   // 98304
    float* wsv1          = (float*)ws;          ws += (size_t)24 * 4096 * 4;          // 393216
    float* wsv2          = (float*)ws;          ws += (size_t)24 * 4096 * 4;
    float* wsv3          = (float*)ws;          ws += (size_t)24 * 4096 * 4;
    int*   wsi12         = (int*)ws;            ws += (size_t)24 * 4096 * 4;
    int*   wsi3          = (int*)ws;            ws += (size_t)24 * 4096 * 4;
    int*   wl_count      = (int*)ws;            ws += 64;
    int*   wl            = (int*)ws;            ws += (size_t)WLCAP * 4;              // 131072
    int*   wlc           = (int*)ws;            ws += (size_t)WLCAP * 4;              // 131072
    char*  EhT           = ws;                  ws += (size_t)HEADS * CODES * 128;    // 6291456
    char*  ElT           = ws;

    prep_ke<<<dim3((HEADS * CODES + 255) / 256), dim3(256), 0, stream>>>(
        ke, (uint4*)EhT, (uint4*)ElT, e2np, m2bf, wl_count);
    dkvb_pass1<<<dim3(768), dim3(256), 0, stream>>>(
        x, EhT, ElT, m2bf, wsv1, wsv2, wsv3, wsi12, wsi3);
    merge_out<<<dim3(768), dim3(256), 0, stream>>>(
        wsv1, wsv2, wsv3, wsi12, wsi3, values, wl_count, wl, wlc, out);
    cand_check<<<dim3(1024), dim3(256), 0, stream>>>(
        x, ke, e2np, values, wl_count, wl, wlc, out);
}

// Round 4
// 247.889 us; speedup vs baseline: 1.0572x; 1.0136x over previous
//
#include <hip/hip_runtime.h>

// DiscreteKeyValueBottleneck on MI355X (gfx950)
// B=4 T=1024 H=12 C=4096 DK=DV=64, N=B*T=4096, DIM=768
//
// Round 10: pass1 was VALU-bound (MfmaUtil 20 / VALUBusy 53; ~88 VALU vs
// 8 MFMA per 32-code group). Changes:
//  * m2 (-e2/2, x64 scale, bf16) folded into El slot k=63 with A-side
//    ab[3][7]=1.0 -> no per-group acc-init movs (zacc C-input), no m2
//    LDS/loads. Dropped residual term ~1e-6 unscaled << TAU budget.
//  * merge_out fused into pass1: block = 64 queries x FULL codebook,
//    waves (qt,half) as round-0; intra-block LDS half-merge + margin flag
//    + values gather in epilogue. 3 kernels total.
//  * prep_ke: 8 threads/code (1536 blocks, was 192 latency-bound);
//    np-exact e2 via parallel residue chains + exact balanced tree;
//    coalesced EhT/ElT stores.
//  * top-3 keeps packed-mantissa indices (6-bit group id); i3 never
//    needed -> no index-3 tracking in the butterfly.

#define HEADS 12
#define CODES 4096
#define DKI   64
#define DVI   64
#define DIMX  768
#define TAUS  5.12e-3f    // 64 * 8e-5 (scores carry the x64 E-scale)
#define WLCAP 32768

typedef short bf16x8 __attribute__((ext_vector_type(8)));
typedef _Float16 f16x8 __attribute__((ext_vector_type(8)));
typedef float f32x16 __attribute__((ext_vector_type(16)));

__device__ __forceinline__ unsigned short f2bf(float f) {   // RNE
    unsigned int u = __float_as_uint(f);
    return (unsigned short)((u + 0x7fff + ((u >> 16) & 1)) >> 16);
}
__device__ __forceinline__ float bf2f(unsigned short h) {
    return __uint_as_float(((unsigned int)h) << 16);
}
__device__ __forceinline__ unsigned short f2h(float f) {    // RNE f32->f16
    _Float16 h = (_Float16)f;
    unsigned short u;
    __builtin_memcpy(&u, &h, 2);
    return u;
}
__device__ __forceinline__ float h2f(unsigned short u) {
    _Float16 h;
    __builtin_memcpy(&h, &u, 2);
    return (float)h;
}

__device__ __forceinline__ void async_load16(const void* g, void* l) {
    __builtin_amdgcn_global_load_lds(
        (const __attribute__((address_space(1))) unsigned int*)g,
        (__attribute__((address_space(3))) unsigned int*)l, 16, 0, 0);
}

// ---------------- numpy bit-exact helpers (fp32, contraction OFF) -----------
__device__ __forceinline__ float np_sumsq64(const float* __restrict__ a) {
#pragma clang fp contract(off)
    float r[8];
#pragma unroll
    for (int j = 0; j < 8; ++j) r[j] = a[j] * a[j];
#pragma unroll
    for (int i = 8; i < 64; i += 8)
#pragma unroll
        for (int j = 0; j < 8; ++j) r[j] += a[i + j] * a[i + j];
    return ((r[0] + r[1]) + (r[2] + r[3])) + ((r[4] + r[5]) + (r[6] + r[7]));
}

__device__ __forceinline__ float np_dot64(const float* __restrict__ xx,
                                          const float* __restrict__ ee) {
#pragma clang fp contract(off)
    float S0 = 0.f, S1 = 0.f, S2 = 0.f, S3 = 0.f;
#pragma unroll
    for (int t = 0; t < 64; t += 16) {
        float p[16];
#pragma unroll
        for (int j = 0; j < 16; ++j) p[j] = xx[t + j] * ee[t + j];
        S0 = p[0] + (p[4] + (p[8]  + (p[12] + S0)));
        S1 = p[1] + (p[5] + (p[9]  + (p[13] + S1)));
        S2 = p[2] + (p[6] + (p[10] + (p[14] + S2)));
        S3 = p[3] + (p[7] + (p[11] + (p[15] + S3)));
    }
    return (S0 + S1) + (S2 + S3);
}

// ---- prep: np-exact e2; Eh(fp16,x64)/El(bf16 residual; k63=m2) layout ------
// Block = 32 codes, 8 threads/code (t: piece p=t>>5, code cw=t&31).
// uint4 units: [((pair*64+gg)*8 + piece)*32 + cc], pair=h*2+half, gg=(c&2047)>>5.
__global__ __launch_bounds__(256) void prep_ke(const float* __restrict__ ke,
                                               uint4* __restrict__ EhT,
                                               uint4* __restrict__ ElT,
                                               float* __restrict__ e2np,
                                               int* __restrict__ wl_count) {
    __shared__ float sq[32][64];
    __shared__ float rr[32][8];
    __shared__ float m2s[32];
    const int t = threadIdx.x;
    if (blockIdx.x == 0 && t == 0) *wl_count = 0;
    const int p = t >> 5, cw = t & 31;
    const int idx = blockIdx.x * 32 + cw;          // all 32 codes share h/half/gg

    float er[8];
    {
        const float4* p4 = reinterpret_cast<const float4*>(
            ke + (size_t)idx * DKI + p * 8);
        float4 v0 = p4[0], v1 = p4[1];
        er[0] = v0.x; er[1] = v0.y; er[2] = v0.z; er[3] = v0.w;
        er[4] = v1.x; er[5] = v1.y; er[6] = v1.z; er[7] = v1.w;
    }
    {
#pragma clang fp contract(off)
#pragma unroll
        for (int j = 0; j < 8; ++j) sq[cw][p * 8 + j] = er[j] * er[j];
    }
    __syncthreads();
    {   // residue chain rho = p : r = ((sq[rho]+sq[8+rho])+sq[16+rho])+...
#pragma clang fp contract(off)
        float r = sq[cw][p];
#pragma unroll
        for (int k = 1; k < 8; ++k) r = r + sq[cw][k * 8 + p];
        rr[cw][p] = r;
    }
    __syncthreads();
    if (p == 0) {
#pragma clang fp contract(off)
        float e2 = ((rr[cw][0] + rr[cw][1]) + (rr[cw][2] + rr[cw][3])) +
                   ((rr[cw][4] + rr[cw][5]) + (rr[cw][6] + rr[cw][7]));
        e2np[idx] = e2;
        m2s[cw] = -32.f * e2;                      // 64 * (-e2/2)
    }
    __syncthreads();

    unsigned int hb[8], lb[8];
#pragma unroll
    for (int j = 0; j < 8; ++j) {
        float fs = er[j] * 64.f;                   // exact (pow2 scale)
        unsigned short hh = f2h(fs);
        hb[j] = hh;
        lb[j] = f2bf(fs - h2f(hh));                // exact residual
    }
    if (p == 7) lb[7] = f2bf(m2s[cw]);             // m2 rides in El slot k=63
    uint4 hv, lv;
    hv.x = hb[0] | (hb[1] << 16); hv.y = hb[2] | (hb[3] << 16);
    hv.z = hb[4] | (hb[5] << 16); hv.w = hb[6] | (hb[7] << 16);
    lv.x = lb[0] | (lb[1] << 16); lv.y = lb[2] | (lb[3] << 16);
    lv.z = lb[4] | (lb[5] << 16); lv.w = lb[6] | (lb[7] << 16);

    const int h = idx >> 12, c = idx & 4095;
    const int half = c >> 11, gg = (c & 2047) >> 5;
    const int pair = h * 2 + half;
    const size_t u4 = ((size_t)(pair * 64 + gg) * 8 + p) * 32 + cw;
    EhT[u4] = hv;
    ElT[u4] = lv;
}

// ---- pass 1: fused scores + top-3 + half-merge + flag + gather -------------
// grid 768 = 12 heads x 64 q-blocks (h = b%12 -> 3 heads/XCD, L2-resident).
// Block: 4 waves, 64 queries, full codebook. Wave w: q-tile qt=w&1 (32 q),
// code half=w>>1 (2048 codes, 64 chunks of 32). Wave w stages (half=w>>1,
// mat=w&1); counted-vmcnt 3-buffer ring (no barrier drain).
__global__ __launch_bounds__(256, 3) void dkvb_pass1(
        const float* __restrict__ x,
        const char* __restrict__ EhT,
        const char* __restrict__ ElT,
        const float* __restrict__ values,
        int* __restrict__ wl_count,
        int* __restrict__ wl,
        int* __restrict__ wlc,
        float* __restrict__ out) {
    __shared__ __align__(16) char ldsbuf[3][16384];  // [ring][half][mat][4096]
    __shared__ float sb1[2][64], sb2[2][64], sb3[2][64];
    __shared__ int   sbi[2][64];
    __shared__ int   fin[64];

    const int tid  = threadIdx.x;
    const int h    = blockIdx.x % 12;
    const int qb   = blockIdx.x / 12;
    const int w    = tid >> 6;
    const int lane = tid & 63;
    const int col  = lane & 31;              // B col (code) / A row (query)
    const int kh   = lane >> 5;              // k-half within K=16 step
    const int qt   = w & 1;
    const int half = w >> 1;
    const int q0   = qb * 64;
    const int pair = h * 2 + half;

    // ---- A fragments: query m = q0+qt*32+col; step t: k = t*16 + kh*8 + j
    const float* xrow = x + (size_t)(q0 + qt * 32 + col) * DIMX + h * DKI;
    f16x8 ah[4]; bf16x8 ab[4];
#pragma unroll
    for (int t = 0; t < 4; ++t) {
        const float* p = xrow + t * 16 + kh * 8;
        float4 v0 = *reinterpret_cast<const float4*>(p);
        float4 v1 = *reinterpret_cast<const float4*>(p + 4);
        float f[8] = {v0.x, v0.y, v0.z, v0.w, v1.x, v1.y, v1.z, v1.w};
#pragma unroll
        for (int j = 0; j < 8; ++j) {
            ah[t][j] = (_Float16)f[j];
            ab[t][j] = (short)f2bf(f[j]);
        }
    }
    if (kh) ab[3][7] = (short)0x3F80;        // 1.0bf16: pairs with El k63 = m2

    // ---- staging: wave w stages matrix (w&1) of half (w>>1) ---------------
    const char* gsrc = ((w & 1) ? ElT : EhT)
                     + (size_t)pair * 262144 + (size_t)lane * 16;
    const unsigned ldso = (unsigned)w * 4096u;   // w == half*2+mat

    char* bA = &ldsbuf[0][0];
    char* bB = &ldsbuf[1][0];
    char* bC = &ldsbuf[2][0];

    auto STAGE = [&](const char* gp, char* lp) {
        async_load16(gp,        lp);
        async_load16(gp + 1024, lp + 1024);
        async_load16(gp + 2048, lp + 2048);
        async_load16(gp + 3072, lp + 3072);
    };
    STAGE(gsrc,        bA + ldso);
    STAGE(gsrc + 4096, bB + ldso);

    f32x16 zacc;
#pragma unroll
    for (int r = 0; r < 16; ++r) zacc[r] = 0.f;

    float bv[16], bv2[16], bv3[16];
#pragma unroll
    for (int r = 0; r < 16; ++r) { bv[r] = -1e30f; bv2[r] = -1e30f; bv3[r] = -1e30f; }

    const int foff = kh * 512 + col * 16;    // + t*1024 (piece 2t+kh)

#pragma unroll 1
    for (int i = 0; i < 64; ++i) {
        // counted prefetch: chunks i, i+1 in flight (4 loads each per wave)
        if (i < 63) { asm volatile("s_waitcnt vmcnt(4)" ::: "memory"); }
        else        { asm volatile("s_waitcnt vmcnt(0)" ::: "memory"); }
        __builtin_amdgcn_sched_barrier(0);
        __builtin_amdgcn_s_barrier();        // chunk i valid for all waves
        __builtin_amdgcn_sched_barrier(0);
        if (i + 2 < 64) STAGE(gsrc + (size_t)(i + 2) * 4096, bC + ldso);

        const char* Bb = bA + half * 8192 + foff;
        f16x8 bh[4]; bf16x8 bl[4];
#pragma unroll
        for (int t = 0; t < 4; ++t) {
            bh[t] = *reinterpret_cast<const f16x8*>(Bb + t * 1024);
            bl[t] = *reinterpret_cast<const bf16x8*>(Bb + 4096 + t * 1024);
        }
        f32x16 acc;
        acc = __builtin_amdgcn_mfma_f32_32x32x16_f16 (ah[0], bh[0], zacc, 0, 0, 0);
        acc = __builtin_amdgcn_mfma_f32_32x32x16_f16 (ah[1], bh[1], acc,  0, 0, 0);
        acc = __builtin_amdgcn_mfma_f32_32x32x16_f16 (ah[2], bh[2], acc,  0, 0, 0);
        acc = __builtin_amdgcn_mfma_f32_32x32x16_f16 (ah[3], bh[3], acc,  0, 0, 0);
        acc = __builtin_amdgcn_mfma_f32_32x32x16_bf16(ab[0], bl[0], acc,  0, 0, 0);
        acc = __builtin_amdgcn_mfma_f32_32x32x16_bf16(ab[1], bl[1], acc,  0, 0, 0);
        acc = __builtin_amdgcn_mfma_f32_32x32x16_bf16(ab[2], bl[2], acc,  0, 0, 0);
        acc = __builtin_amdgcn_mfma_f32_32x32x16_bf16(ab[3], bl[3], acc,  0, 0, 0);

        // top-3, index packed into mantissa LSBs: 4 VALU/score
        unsigned enc = (unsigned)i;          // 6-bit chunk id
#pragma unroll
        for (int r = 0; r < 16; ++r) {
            float sp = __uint_as_float(
                (__float_as_uint(acc[r]) & 0xFFFFFFC0u) | enc);
            bv3[r] = __builtin_amdgcn_fmed3f(bv3[r], sp, bv2[r]);  // old v2
            bv2[r] = __builtin_amdgcn_fmed3f(bv2[r], sp, bv[r]);   // old v1
            bv[r]  = fmaxf(bv[r], sp);
        }
        char* tsw = bA; bA = bB; bB = bC; bC = tsw;   // rotate ring
    }

    // ---- decode packed indices, cross-col top-3 butterfly (no i3) ----------
    int bi1[16], bi2[16];
#pragma unroll
    for (int r = 0; r < 16; ++r) {
        bi1[r] = (int)(__float_as_uint(bv[r])  & 63u) * 32 + col;  // within-half
        bi2[r] = (int)(__float_as_uint(bv2[r]) & 63u) * 32 + col;
    }
#pragma unroll
    for (int r = 0; r < 16; ++r) {
#pragma unroll
        for (int m = 1; m <= 16; m <<= 1) {
            float p1 = __shfl_xor(bv[r],  m, 64);
            float p2 = __shfl_xor(bv2[r], m, 64);
            float p3 = __shfl_xor(bv3[r], m, 64);
            int   q1 = __shfl_xor(bi1[r], m, 64);
            int   q2 = __shfl_xor(bi2[r], m, 64);
            bool t1 = p1 > bv[r];
            float w1 = t1 ? p1 : bv[r];   int j1 = t1 ? q1 : bi1[r];
            float l1 = t1 ? bv[r] : p1;   int k1 = t1 ? bi1[r] : q1;
            float s2 = t1 ? p2 : bv2[r];  int u2 = t1 ? q2 : bi2[r];
            bool t2 = s2 > l1;
            float w2 = t2 ? s2 : l1;      int j2 = t2 ? u2 : k1;
            float l2 = t2 ? l1 : s2;
            float s3 = t2 ? (t1 ? p3 : bv3[r]) : (t1 ? bv2[r] : p2);
            bool t3 = s3 > l2;
            float w3 = t3 ? s3 : l2;
            bv[r] = w1; bi1[r] = j1;
            bv2[r] = w2; bi2[r] = j2;
            bv3[r] = w3;
        }
    }
    if (col == 0) {                          // lanes 0 and 32
#pragma unroll
        for (int r = 0; r < 16; ++r) {
            int row = (r & 3) + 8 * (r >> 2) + 4 * kh;
            int qq = qt * 32 + row;
            sb1[half][qq] = bv[r];
            sb2[half][qq] = bv2[r];
            sb3[half][qq] = bv3[r];
            sbi[half][qq] = (bi1[r] << 16) | bi2[r];
        }
    }
    __syncthreads();

    // ---- merge the two code halves, flag small margins ---------------------
    if (tid < 64) {
        float a1 = sb1[0][tid], a2 = sb2[0][tid], a3 = sb3[0][tid];
        int am = sbi[0][tid];
        int ia1 = (am >> 16) & 0xffff, ia2 = am & 0xffff;
        float c1 = sb1[1][tid], c2 = sb2[1][tid], c3 = sb3[1][tid];
        int cm = sbi[1][tid];
        int ib1 = ((cm >> 16) & 0xffff) + 2048, ib2 = (cm & 0xffff) + 2048;
        // exact top-3 merge of two sorted triples (tie at rank1 -> half 0)
        bool t1 = c1 > a1;
        float v1 = t1 ? c1 : a1;  int i1 = t1 ? ib1 : ia1;
        float l1 = t1 ? a1 : c1;  int k1 = t1 ? ia1 : ib1;
        float s2 = t1 ? c2 : a2;  int u2 = t1 ? ib2 : ia2;
        bool t2 = s2 > l1;
        float v2 = t2 ? s2 : l1;  int i2 = t2 ? u2 : k1;
        float l2 = t2 ? l1 : s2;
        float s3 = t2 ? (t1 ? c3 : a3) : (t1 ? a2 : c2);
        bool t3 = s3 > l2;
        float v3 = t3 ? s3 : l2;
        fin[tid] = i1;
        if (v1 - v2 < TAUS) {
            int slot = atomicAdd(wl_count, 1);
            if (slot < WLCAP) {
                wl[slot]  = (h << 16) | (q0 + tid);
                wlc[slot] = (v1 - v3 < TAUS) ? -1 : ((i1 << 16) | i2);
            }
        }
    }
    __syncthreads();

    // ---- gather values[h, fin[q], :] -> out; 64 rows x 16 float4 -----------
#pragma unroll
    for (int k = 0; k < 4; ++k) {
        int f   = tid + k * 256;
        int row = f >> 4;
        int cl  = (f & 15) << 2;
        int idx = fin[row];
        float4 v = *reinterpret_cast<const float4*>(
            values + (size_t)h * CODES * DVI + (size_t)idx * DVI + cl);
        *reinterpret_cast<float4*>(
            out + (size_t)(q0 + row) * DIMX + h * DVI + cl) = v;
    }
}

// ---- pass 2: np-exact candidate check, one wave per flagged entry ----------
// wlc >= 0: two candidates (lanes 0,1 run the np chains in lockstep).
// wlc == -1: rare near-tie fallback -> full 4096-code np scan by the wave,
// packed-key min butterfly reproduces jnp.argmin first-index tie-break.
__global__ __launch_bounds__(256) void cand_check(const float* __restrict__ x,
                                                  const float* __restrict__ ke,
                                                  const float* __restrict__ e2np,
                                                  const float* __restrict__ values,
                                                  const int* __restrict__ wl_count,
                                                  const int* __restrict__ wl,
                                                  const int* __restrict__ wlc,
                                                  float* __restrict__ out) {
    __shared__ float xs[4][DKI];
    const int t = threadIdx.x, w = t >> 6, lane = t & 63;
    int cnt = *wl_count;
    if (cnt > WLCAP) cnt = WLCAP;

    for (int e = blockIdx.x * 4 + w; e < cnt; e += gridDim.x * 4) {
        int ent = wl[e];
        int h = ent >> 16, nq = ent & 0xffff;
        int cp = wlc[e];
        if (lane < 16) {
            float4 v = *reinterpret_cast<const float4*>(
                x + (size_t)nq * DIMX + h * DKI + lane * 4);
            *reinterpret_cast<float4*>(&xs[w][lane * 4]) = v;
        }
        asm volatile("s_waitcnt lgkmcnt(0)" ::: "memory");
        __builtin_amdgcn_sched_barrier(0);

        int win;
        if (cp >= 0) {
            int i1 = (cp >> 16) & 0xffff, i2 = cp & 0xffff;
            float d2 = 0.f;
            if (lane < 2) {
                int myc = lane ? i2 : i1;
                float er[DKI];
                const float4* p = reinterpret_cast<const float4*>(
                    ke + ((size_t)h * CODES + myc) * DKI);
#pragma unroll
                for (int i = 0; i < DKI / 4; ++i) {
                    float4 v = p[i];
                    er[i * 4 + 0] = v.x; er[i * 4 + 1] = v.y;
                    er[i * 4 + 2] = v.z; er[i * 4 + 3] = v.w;
                }
                float x2 = np_sumsq64(xs[w]);
                float dot = np_dot64(xs[w], er);
                {
#pragma clang fp contract(off)
                    d2 = (x2 - 2.0f * dot) + e2np[h * CODES + myc];
                }
            }
            float dA = __shfl(d2, 0, 64);
            float dB = __shfl(d2, 1, 64);
            win = (dB < dA || (dB == dA && i2 < i1)) ? i2 : i1;
        } else {
            float x2 = np_sumsq64(xs[w]);
            unsigned long long best = ~0ULL;
#pragma unroll 1
            for (int it = 0; it < 64; ++it) {
                int c = it * 64 + lane;
                float er[DKI];
                const float4* p = reinterpret_cast<const float4*>(
                    ke + ((size_t)h * CODES + c) * DKI);
#pragma unroll
                for (int i = 0; i < DKI / 4; ++i) {
                    float4 v = p[i];
                    er[i * 4 + 0] = v.x; er[i * 4 + 1] = v.y;
                    er[i * 4 + 2] = v.z; er[i * 4 + 3] = v.w;
                }
                float dot = np_dot64(xs[w], er);
                float d2;
                {
#pragma clang fp contract(off)
                    d2 = (x2 - 2.0f * dot) + e2np[h * CODES + c];
                }
                unsigned u = __float_as_uint(d2);
                unsigned key = (u & 0x80000000u) ? ~u : (u | 0x80000000u);
                unsigned long long pk =
                    ((unsigned long long)key << 32) | (unsigned)c;
                best = pk < best ? pk : best;
            }
#pragma unroll
            for (int m = 1; m <= 32; m <<= 1) {
                unsigned long long o =
                    (unsigned long long)__shfl_xor((long long)best, m, 64);
                best = o < best ? o : best;
            }
            win = (int)(best & 0xFFFFFFFFULL);
        }
        if (lane < 16) {
            float4 v = *reinterpret_cast<const float4*>(
                values + ((size_t)h * CODES + win) * DVI + lane * 4);
            *reinterpret_cast<float4*>(
                out + (size_t)nq * DIMX + h * DVI + lane * 4) = v;
        }
    }
}

extern "C" void kernel_launch(void* const* d_in, const int* in_sizes, int n_in,
                              void* d_out, int out_size, void* d_ws, size_t ws_size,
                              hipStream_t stream) {
    const float* x      = (const float*)d_in[0];
    // d_in[1] = mask (all ones; unused)
    const float* ke     = (const float*)d_in[2];
    const float* values = (const float*)d_in[3];
    // d_in[4] = key_optim (unused)
    float* out = (float*)d_out;

    char* ws = (char*)d_ws;
    float* e2np     = (float*)ws; ws += (size_t)HEADS * CODES * 4;      // 196608
    int*   wl_count = (int*)ws;   ws += 64;
    int*   wl       = (int*)ws;   ws += (size_t)WLCAP * 4;              // 131072
    int*   wlc      = (int*)ws;   ws += (size_t)WLCAP * 4;              // 131072
    char*  EhT      = ws;         ws += (size_t)HEADS * CODES * 128;    // 6291456
    char*  ElT      = ws;

    prep_ke<<<dim3(HEADS * CODES / 32), dim3(256), 0, stream>>>(
        ke, (uint4*)EhT, (uint4*)ElT, e2np, wl_count);
    dkvb_pass1<<<dim3(768), dim3(256), 0, stream>>>(
        x, EhT, ElT, values, wl_count, wl, wlc, out);
    cand_check<<<dim3(1024), dim3(256), 0, stream>>>(
        x, ke, e2np, values, wl_count, wl, wlc, out);
}

// Round 5
// 217.810 us; speedup vs baseline: 1.2032x; 1.1381x over previous
//
#include <hip/hip_runtime.h>

// DiscreteKeyValueBottleneck on MI355X (gfx950)
// B=4 T=1024 H=12 C=4096 DK=DV=64, N=B*T=4096, DIM=768
//
// Round 11: pass1 was barrier-bound (~1000 cyc per barrier round; r3 32
// barriers=107us vs r4 64 barriers=121us, MFMA const 20us). Changes:
//  * fp16-ONLY scores: 4 MFMA/tile (x fp16 x Eh fp16, both rel 2^-11) --
//    dot error rms ~4.3e-6 unscaled; TAU raised 8e-5 -> 1.2e-4 (same
//    28x safety factor that held absmax=0). El product dropped entirely.
//  * m2 (-e2/2) via 5th K16 bf16 MFMA: A=[1,0..] const, B=[m2bf,0..]
//    (1 ushort load + 1 MFMA; no acc-init movs, no m2 LDS).
//  * wave-private REGISTER staging: each lane global_load_dwordx4's its
//    own B-fragments (prep stores fragment-ordered; wave load = 1KB
//    contiguous). NO LDS staging, NO s_barrier, no ds_read in main loop;
//    named-reg double buffer (unroll-2, static indexing). Waves free-run;
//    compiler inserts counted vmcnt. E read per q-tile wave (786MB L2,
//    XCD-pinned 1.5MB hot set) -- cheaper than the barrier tax.
//  * top-3 + packed-mantissa-index, fused half-merge/flag/gather, and
//    np-exact 2-candidate recheck unchanged.

#define HEADS 12
#define CODES 4096
#define DKI   64
#define DVI   64
#define DIMX  768
#define TAUS  7.68e-3f    // 64 * 1.2e-4 (scores carry the x64 E-scale)
#define WLCAP 32768

typedef short bf16x8 __attribute__((ext_vector_type(8)));
typedef _Float16 f16x8 __attribute__((ext_vector_type(8)));
typedef float f32x16 __attribute__((ext_vector_type(16)));

__device__ __forceinline__ unsigned short f2bf(float f) {   // RNE
    unsigned int u = __float_as_uint(f);
    return (unsigned short)((u + 0x7fff + ((u >> 16) & 1)) >> 16);
}
__device__ __forceinline__ unsigned short f2h(float f) {    // RNE f32->f16
    _Float16 h = (_Float16)f;
    unsigned short u;
    __builtin_memcpy(&u, &h, 2);
    return u;
}
__device__ __forceinline__ float h2f(unsigned short u) {
    _Float16 h;
    __builtin_memcpy(&h, &u, 2);
    return (float)h;
}
__device__ __forceinline__ f16x8 as_f16x8(uint4 v) {
    union { uint4 u; f16x8 h; } c; c.u = v; return c.h;
}

// ---------------- numpy bit-exact helpers (fp32, contraction OFF) -----------
__device__ __forceinline__ float np_sumsq64(const float* __restrict__ a) {
#pragma clang fp contract(off)
    float r[8];
#pragma unroll
    for (int j = 0; j < 8; ++j) r[j] = a[j] * a[j];
#pragma unroll
    for (int i = 8; i < 64; i += 8)
#pragma unroll
        for (int j = 0; j < 8; ++j) r[j] += a[i + j] * a[i + j];
    return ((r[0] + r[1]) + (r[2] + r[3])) + ((r[4] + r[5]) + (r[6] + r[7]));
}

__device__ __forceinline__ float np_dot64(const float* __restrict__ xx,
                                          const float* __restrict__ ee) {
#pragma clang fp contract(off)
    float S0 = 0.f, S1 = 0.f, S2 = 0.f, S3 = 0.f;
#pragma unroll
    for (int t = 0; t < 64; t += 16) {
        float p[16];
#pragma unroll
        for (int j = 0; j < 16; ++j) p[j] = xx[t + j] * ee[t + j];
        S0 = p[0] + (p[4] + (p[8]  + (p[12] + S0)));
        S1 = p[1] + (p[5] + (p[9]  + (p[13] + S1)));
        S2 = p[2] + (p[6] + (p[10] + (p[14] + S2)));
        S3 = p[3] + (p[7] + (p[11] + (p[15] + S3)));
    }
    return (S0 + S1) + (S2 + S3);
}

// ---- prep: np-exact e2; Eh(fp16,x64) fragment layout; m2bf(-32*e2) ---------
// Block = 32 codes, 8 threads/code (t: piece p=t>>5, code cw=t&31).
// uint4 units: [((pair*64+gg)*8 + piece)*32 + cc], pair=h*2+half, gg=(c&2047)>>5.
__global__ __launch_bounds__(256) void prep_ke(const float* __restrict__ ke,
                                               uint4* __restrict__ EhT,
                                               float* __restrict__ e2np,
                                               unsigned short* __restrict__ m2bf,
                                               int* __restrict__ wl_count) {
    __shared__ float sq[32][64];
    __shared__ float rr[32][8];
    const int t = threadIdx.x;
    if (blockIdx.x == 0 && t == 0) *wl_count = 0;
    const int p = t >> 5, cw = t & 31;
    const int idx = blockIdx.x * 32 + cw;          // all 32 codes share h/half/gg

    float er[8];
    {
        const float4* p4 = reinterpret_cast<const float4*>(
            ke + (size_t)idx * DKI + p * 8);
        float4 v0 = p4[0], v1 = p4[1];
        er[0] = v0.x; er[1] = v0.y; er[2] = v0.z; er[3] = v0.w;
        er[4] = v1.x; er[5] = v1.y; er[6] = v1.z; er[7] = v1.w;
    }
    {
#pragma clang fp contract(off)
#pragma unroll
        for (int j = 0; j < 8; ++j) sq[cw][p * 8 + j] = er[j] * er[j];
    }
    __syncthreads();
    {   // residue chain rho = p : r = ((sq[rho]+sq[8+rho])+sq[16+rho])+...
#pragma clang fp contract(off)
        float r = sq[cw][p];
#pragma unroll
        for (int k = 1; k < 8; ++k) r = r + sq[cw][k * 8 + p];
        rr[cw][p] = r;
    }
    __syncthreads();
    const int h = idx >> 12, c = idx & 4095;
    const int half = c >> 11, gg = (c & 2047) >> 5;
    const int pair = h * 2 + half;
    if (p == 0) {
#pragma clang fp contract(off)
        float e2 = ((rr[cw][0] + rr[cw][1]) + (rr[cw][2] + rr[cw][3])) +
                   ((rr[cw][4] + rr[cw][5]) + (rr[cw][6] + rr[cw][7]));
        e2np[idx] = e2;
        m2bf[(size_t)pair * 2048 + (c & 2047)] = f2bf(-32.f * e2);
    }

    unsigned int hb[8];
#pragma unroll
    for (int j = 0; j < 8; ++j)
        hb[j] = f2h(er[j] * 64.f);                 // exact pow2 scale
    uint4 hv;
    hv.x = hb[0] | (hb[1] << 16); hv.y = hb[2] | (hb[3] << 16);
    hv.z = hb[4] | (hb[5] << 16); hv.w = hb[6] | (hb[7] << 16);
    EhT[((size_t)(pair * 64 + gg) * 8 + p) * 32 + cw] = hv;
}

// ---- pass 1: fp16-only MFMA, wave-private reg staging, barrier-free --------
// grid 768 = 12 heads x 64 q-blocks (h=b%12 -> 3 heads/XCD, L2-resident).
// Block: 4 waves, 64 queries, full codebook; wave w: qt=w&1, half=w>>1,
// covers 32q x 2048 codes in 64 chunks of 32. No LDS/barriers in main loop.
__global__ __launch_bounds__(256, 3) void dkvb_pass1(
        const float* __restrict__ x,
        const char* __restrict__ EhT,
        const unsigned short* __restrict__ m2bf,
        const float* __restrict__ values,
        int* __restrict__ wl_count,
        int* __restrict__ wl,
        int* __restrict__ wlc,
        float* __restrict__ out) {
    __shared__ float sb1[2][64], sb2[2][64], sb3[2][64];
    __shared__ int   sbi[2][64];
    __shared__ int   fin[64];

    const int tid  = threadIdx.x;
    const int h    = blockIdx.x % 12;
    const int qb   = blockIdx.x / 12;
    const int w    = tid >> 6;
    const int lane = tid & 63;
    const int col  = lane & 31;              // B col (code) / A row (query)
    const int kh   = lane >> 5;              // k-half within K=16 step
    const int qt   = w & 1;
    const int half = w >> 1;
    const int q0   = qb * 64;
    const int pair = h * 2 + half;

    // ---- A fragments (fp16): query m = q0+qt*32+col; k = t*16 + kh*8 + j
    const float* xrow = x + (size_t)(q0 + qt * 32 + col) * DIMX + h * DKI;
    f16x8 ah[4];
#pragma unroll
    for (int t = 0; t < 4; ++t) {
        const float* p = xrow + t * 16 + kh * 8;
        float4 v0 = *reinterpret_cast<const float4*>(p);
        float4 v1 = *reinterpret_cast<const float4*>(p + 4);
        f16x8 hv;
        hv[0] = (_Float16)v0.x; hv[1] = (_Float16)v0.y;
        hv[2] = (_Float16)v0.z; hv[3] = (_Float16)v0.w;
        hv[4] = (_Float16)v1.x; hv[5] = (_Float16)v1.y;
        hv[6] = (_Float16)v1.z; hv[7] = (_Float16)v1.w;
        ah[t] = hv;
    }
    // m2 A-side const fragment: row r, k=0 slot = 1.0bf16 (kh=0 lanes only)
    const bf16x8 am2 = (bf16x8){(short)(kh ? 0 : 0x3F80), 0, 0, 0, 0, 0, 0, 0};

    const char* gE = EhT + (size_t)pair * 262144
                   + (size_t)kh * 512 + (size_t)col * 16;
    const unsigned short* gm = m2bf + (size_t)pair * 2048 + col;

    f32x16 zacc;
#pragma unroll
    for (int r = 0; r < 16; ++r) zacc[r] = 0.f;

    float bv[16], bv2[16], bv3[16];
#pragma unroll
    for (int r = 0; r < 16; ++r) { bv[r] = -1e30f; bv2[r] = -1e30f; bv3[r] = -1e30f; }

    auto LOADF = [&](int i, uint4& e0, uint4& e1, uint4& e2, uint4& e3,
                     unsigned short& mA) {
        const char* p = gE + (size_t)i * 4096;
        e0 = *reinterpret_cast<const uint4*>(p);
        e1 = *reinterpret_cast<const uint4*>(p + 1024);
        e2 = *reinterpret_cast<const uint4*>(p + 2048);
        e3 = *reinterpret_cast<const uint4*>(p + 3072);
        mA = gm[i * 32];
    };
    auto COMPUTE = [&](int i, uint4 e0, uint4 e1, uint4 e2, uint4 e3,
                       unsigned short mA) {
        bf16x8 bm = (bf16x8){(short)(kh ? 0 : mA), 0, 0, 0, 0, 0, 0, 0};
        f32x16 acc;
        acc = __builtin_amdgcn_mfma_f32_32x32x16_bf16(am2,   bm,          zacc, 0, 0, 0);
        acc = __builtin_amdgcn_mfma_f32_32x32x16_f16 (ah[0], as_f16x8(e0), acc, 0, 0, 0);
        acc = __builtin_amdgcn_mfma_f32_32x32x16_f16 (ah[1], as_f16x8(e1), acc, 0, 0, 0);
        acc = __builtin_amdgcn_mfma_f32_32x32x16_f16 (ah[2], as_f16x8(e2), acc, 0, 0, 0);
        acc = __builtin_amdgcn_mfma_f32_32x32x16_f16 (ah[3], as_f16x8(e3), acc, 0, 0, 0);
        unsigned enc = (unsigned)i;          // 6-bit chunk id in mantissa LSBs
#pragma unroll
        for (int r = 0; r < 16; ++r) {
            float sp = __uint_as_float(
                (__float_as_uint(acc[r]) & 0xFFFFFFC0u) | enc);
            bv3[r] = __builtin_amdgcn_fmed3f(bv3[r], sp, bv2[r]);  // old v2
            bv2[r] = __builtin_amdgcn_fmed3f(bv2[r], sp, bv[r]);   // old v1
            bv[r]  = fmaxf(bv[r], sp);
        }
    };

    uint4 A0, A1, A2, A3, B0, B1, B2, B3;
    unsigned short Am, Bm;
    LOADF(0, A0, A1, A2, A3, Am);
#pragma unroll 1
    for (int i = 0; i < 64; i += 2) {        // named-reg dbuf, static indexing
        LOADF(i + 1, B0, B1, B2, B3, Bm);
        COMPUTE(i, A0, A1, A2, A3, Am);
        if (i + 2 < 64) LOADF(i + 2, A0, A1, A2, A3, Am);
        COMPUTE(i + 1, B0, B1, B2, B3, Bm);
    }

    // ---- decode packed indices, cross-col top-3 butterfly (no i3) ----------
    int bi1[16], bi2[16];
#pragma unroll
    for (int r = 0; r < 16; ++r) {
        bi1[r] = (int)(__float_as_uint(bv[r])  & 63u) * 32 + col;  // within-half
        bi2[r] = (int)(__float_as_uint(bv2[r]) & 63u) * 32 + col;
    }
#pragma unroll
    for (int r = 0; r < 16; ++r) {
#pragma unroll
        for (int m = 1; m <= 16; m <<= 1) {
            float p1 = __shfl_xor(bv[r],  m, 64);
            float p2 = __shfl_xor(bv2[r], m, 64);
            float p3 = __shfl_xor(bv3[r], m, 64);
            int   q1 = __shfl_xor(bi1[r], m, 64);
            int   q2 = __shfl_xor(bi2[r], m, 64);
            bool t1 = p1 > bv[r];
            float w1 = t1 ? p1 : bv[r];   int j1 = t1 ? q1 : bi1[r];
            float l1 = t1 ? bv[r] : p1;   int k1 = t1 ? bi1[r] : q1;
            float s2 = t1 ? p2 : bv2[r];  int u2 = t1 ? q2 : bi2[r];
            bool t2 = s2 > l1;
            float w2 = t2 ? s2 : l1;      int j2 = t2 ? u2 : k1;
            float l2 = t2 ? l1 : s2;
            float s3 = t2 ? (t1 ? p3 : bv3[r]) : (t1 ? bv2[r] : p2);
            bool t3 = s3 > l2;
            float w3 = t3 ? s3 : l2;
            bv[r] = w1; bi1[r] = j1;
            bv2[r] = w2; bi2[r] = j2;
            bv3[r] = w3;
        }
    }
    if (col == 0) {                          // lanes 0 and 32
#pragma unroll
        for (int r = 0; r < 16; ++r) {
            int row = (r & 3) + 8 * (r >> 2) + 4 * kh;
            int qq = qt * 32 + row;
            sb1[half][qq] = bv[r];
            sb2[half][qq] = bv2[r];
            sb3[half][qq] = bv3[r];
            sbi[half][qq] = (bi1[r] << 16) | bi2[r];
        }
    }
    __syncthreads();

    // ---- merge the two code halves, flag small margins ---------------------
    if (tid < 64) {
        float a1 = sb1[0][tid], a2 = sb2[0][tid], a3 = sb3[0][tid];
        int am = sbi[0][tid];
        int ia1 = (am >> 16) & 0xffff, ia2 = am & 0xffff;
        float c1 = sb1[1][tid], c2 = sb2[1][tid], c3 = sb3[1][tid];
        int cm = sbi[1][tid];
        int ib1 = ((cm >> 16) & 0xffff) + 2048, ib2 = (cm & 0xffff) + 2048;
        // exact top-3 merge of two sorted triples (tie at rank1 -> half 0)
        bool t1 = c1 > a1;
        float v1 = t1 ? c1 : a1;  int i1 = t1 ? ib1 : ia1;
        float l1 = t1 ? a1 : c1;  int k1 = t1 ? ia1 : ib1;
        float s2 = t1 ? c2 : a2;  int u2 = t1 ? ib2 : ia2;
        bool t2 = s2 > l1;
        float v2 = t2 ? s2 : l1;  int i2 = t2 ? u2 : k1;
        float l2 = t2 ? l1 : s2;
        float s3 = t2 ? (t1 ? c3 : a3) : (t1 ? a2 : c2);
        bool t3 = s3 > l2;
        float v3 = t3 ? s3 : l2;
        fin[tid] = i1;
        if (v1 - v2 < TAUS) {
            int slot = atomicAdd(wl_count, 1);
            if (slot < WLCAP) {
                wl[slot]  = (h << 16) | (q0 + tid);
                wlc[slot] = (v1 - v3 < TAUS) ? -1 : ((i1 << 16) | i2);
            }
        }
    }
    __syncthreads();

    // ---- gather values[h, fin[q], :] -> out; 64 rows x 16 float4 -----------
#pragma unroll
    for (int k = 0; k < 4; ++k) {
        int f   = tid + k * 256;
        int row = f >> 4;
        int cl  = (f & 15) << 2;
        int idx = fin[row];
        float4 v = *reinterpret_cast<const float4*>(
            values + (size_t)h * CODES * DVI + (size_t)idx * DVI + cl);
        *reinterpret_cast<float4*>(
            out + (size_t)(q0 + row) * DIMX + h * DVI + cl) = v;
    }
}

// ---- pass 2: np-exact candidate check, one wave per flagged entry ----------
// wlc >= 0: two candidates (lanes 0,1 run the np chains in lockstep).
// wlc == -1: rare near-tie fallback -> full 4096-code np scan by the wave,
// packed-key min butterfly reproduces jnp.argmin first-index tie-break.
__global__ __launch_bounds__(256) void cand_check(const float* __restrict__ x,
                                                  const float* __restrict__ ke,
                                                  const float* __restrict__ e2np,
                                                  const float* __restrict__ values,
                                                  const int* __restrict__ wl_count,
                                                  const int* __restrict__ wl,
                                                  const int* __restrict__ wlc,
                                                  float* __restrict__ out) {
    __shared__ float xs[4][DKI];
    const int t = threadIdx.x, w = t >> 6, lane = t & 63;
    int cnt = *wl_count;
    if (cnt > WLCAP) cnt = WLCAP;

    for (int e = blockIdx.x * 4 + w; e < cnt; e += gridDim.x * 4) {
        int ent = wl[e];
        int h = ent >> 16, nq = ent & 0xffff;
        int cp = wlc[e];
        if (lane < 16) {
            float4 v = *reinterpret_cast<const float4*>(
                x + (size_t)nq * DIMX + h * DKI + lane * 4);
            *reinterpret_cast<float4*>(&xs[w][lane * 4]) = v;
        }
        asm volatile("s_waitcnt lgkmcnt(0)" ::: "memory");
        __builtin_amdgcn_sched_barrier(0);

        int win;
        if (cp >= 0) {
            int i1 = (cp >> 16) & 0xffff, i2 = cp & 0xffff;
            float d2 = 0.f;
            if (lane < 2) {
                int myc = lane ? i2 : i1;
                float er[DKI];
                const float4* p = reinterpret_cast<const float4*>(
                    ke + ((size_t)h * CODES + myc) * DKI);
#pragma unroll
                for (int i = 0; i < DKI / 4; ++i) {
                    float4 v = p[i];
                    er[i * 4 + 0] = v.x; er[i * 4 + 1] = v.y;
                    er[i * 4 + 2] = v.z; er[i * 4 + 3] = v.w;
                }
                float x2 = np_sumsq64(xs[w]);
                float dot = np_dot64(xs[w], er);
                {
#pragma clang fp contract(off)
                    d2 = (x2 - 2.0f * dot) + e2np[h * CODES + myc];
                }
            }
            float dA = __shfl(d2, 0, 64);
            float dB = __shfl(d2, 1, 64);
            win = (dB < dA || (dB == dA && i2 < i1)) ? i2 : i1;
        } else {
            float x2 = np_sumsq64(xs[w]);
            unsigned long long best = ~0ULL;
#pragma unroll 1
            for (int it = 0; it < 64; ++it) {
                int c = it * 64 + lane;
                float er[DKI];
                const float4* p = reinterpret_cast<const float4*>(
                    ke + ((size_t)h * CODES + c) * DKI);
#pragma unroll
                for (int i = 0; i < DKI / 4; ++i) {
                    float4 v = p[i];
                    er[i * 4 + 0] = v.x; er[i * 4 + 1] = v.y;
                    er[i * 4 + 2] = v.z; er[i * 4 + 3] = v.w;
                }
                float dot = np_dot64(xs[w], er);
                float d2;
                {
#pragma clang fp contract(off)
                    d2 = (x2 - 2.0f * dot) + e2np[h * CODES + c];
                }
                unsigned u = __float_as_uint(d2);
                unsigned key = (u & 0x80000000u) ? ~u : (u | 0x80000000u);
                unsigned long long pk =
                    ((unsigned long long)key << 32) | (unsigned)c;
                best = pk < best ? pk : best;
            }
#pragma unroll
            for (int m = 1; m <= 32; m <<= 1) {
                unsigned long long o =
                    (unsigned long long)__shfl_xor((long long)best, m, 64);
                best = o < best ? o : best;
            }
            win = (int)(best & 0xFFFFFFFFULL);
        }
        if (lane < 16) {
            float4 v = *reinterpret_cast<const float4*>(
                values + ((size_t)h * CODES + win) * DVI + lane * 4);
            *reinterpret_cast<float4*>(
                out + (size_t)nq * DIMX + h * DVI + lane * 4) = v;
        }
    }
}

extern "C" void kernel_launch(void* const* d_in, const int* in_sizes, int n_in,
                              void* d_out, int out_size, void* d_ws, size_t ws_size,
                              hipStream_t stream) {
    const float* x      = (const float*)d_in[0];
    // d_in[1] = mask (all ones; unused)
    const float* ke     = (const float*)d_in[2];
    const float* values = (const float*)d_in[3];
    // d_in[4] = key_optim (unused)
    float* out = (float*)d_out;

    char* ws = (char*)d_ws;
    float* e2np          = (float*)ws;          ws += (size_t)HEADS * CODES * 4;      // 196608
    unsigned short* m2bf = (unsigned short*)ws; ws += (size_t)HEADS * 2 * 2048 * 2;   // 98304
    int*   wl_count      = (int*)ws;            ws += 64;
    int*   wl            = (int*)ws;            ws += (size_t)WLCAP * 4;              // 131072
    int*   wlc           = (int*)ws;            ws += (size_t)WLCAP * 4;              // 131072
    char*  EhT           = ws;                  ws += (size_t)HEADS * CODES * 128;    // 6291456

    prep_ke<<<dim3(HEADS * CODES / 32), dim3(256), 0, stream>>>(
        ke, (uint4*)EhT, e2np, m2bf, wl_count);
    dkvb_pass1<<<dim3(768), dim3(256), 0, stream>>>(
        x, EhT, m2bf, values, wl_count, wl, wlc, out);
    cand_check<<<dim3(1024), dim3(256), 0, stream>>>(
        x, ke, e2np, values, wl_count, wl, wlc, out);
}

// Round 6
// 197.882 us; speedup vs baseline: 1.3244x; 1.1007x over previous
//
#include <hip/hip_runtime.h>

// DiscreteKeyValueBottleneck on MI355X (gfx950)
// B=4 T=1024 H=12 C=4096 DK=DV=64, N=B*T=4096, DIM=768
//
// Round 12: poles were cand_check (87us serial fallback tail, occupancy 1%)
// and pass1 grid starvation (768 blocks = 3/CU, occupancy 23%). Changes:
//  * pass1: grid 1536 = 12 heads x 128 q-blocks of 32 queries; 4 waves =
//    4 code QUARTERS (1024 codes, 32 chunks). Same barrier-free reg-staged
//    loop; 6 blocks/CU. Epilogue: 4-way sorted-triple merge (tie -> lower
//    quarter = lower code), flag, gather.
//  * recheck split: 2-cand entries -> wl (cand_check, branch-free);
//    near-ties (v1-v3 < TAUS) -> wlf; np_full runs ONE WAVE per
//    (entry, 1/8 codebook) with packed-key atomicMin (np-exact d2,
//    jnp.argmin tie-break); np_fin gathers winners. Serial depth 64 -> 8.
//  * fp16-only scores (4 MFMA + m2-MFMA), packed-mantissa top-3, TAU
//    1.2e-4 — all unchanged from round 11.

#define HEADS 12
#define CODES 4096
#define DKI   64
#define DVI   64
#define DIMX  768
#define TAUS  7.68e-3f    // 64 * 1.2e-4 (scores carry the x64 E-scale)
#define WLCAP 32768

typedef short bf16x8 __attribute__((ext_vector_type(8)));
typedef _Float16 f16x8 __attribute__((ext_vector_type(8)));
typedef float f32x16 __attribute__((ext_vector_type(16)));

__device__ __forceinline__ unsigned short f2bf(float f) {   // RNE
    unsigned int u = __float_as_uint(f);
    return (unsigned short)((u + 0x7fff + ((u >> 16) & 1)) >> 16);
}
__device__ __forceinline__ unsigned short f2h(float f) {    // RNE f32->f16
    _Float16 h = (_Float16)f;
    unsigned short u;
    __builtin_memcpy(&u, &h, 2);
    return u;
}
__device__ __forceinline__ f16x8 as_f16x8(uint4 v) {
    union { uint4 u; f16x8 h; } c; c.u = v; return c.h;
}

// ---------------- numpy bit-exact helpers (fp32, contraction OFF) -----------
__device__ __forceinline__ float np_sumsq64(const float* __restrict__ a) {
#pragma clang fp contract(off)
    float r[8];
#pragma unroll
    for (int j = 0; j < 8; ++j) r[j] = a[j] * a[j];
#pragma unroll
    for (int i = 8; i < 64; i += 8)
#pragma unroll
        for (int j = 0; j < 8; ++j) r[j] += a[i + j] * a[i + j];
    return ((r[0] + r[1]) + (r[2] + r[3])) + ((r[4] + r[5]) + (r[6] + r[7]));
}

__device__ __forceinline__ float np_dot64(const float* __restrict__ xx,
                                          const float* __restrict__ ee) {
#pragma clang fp contract(off)
    float S0 = 0.f, S1 = 0.f, S2 = 0.f, S3 = 0.f;
#pragma unroll
    for (int t = 0; t < 64; t += 16) {
        float p[16];
#pragma unroll
        for (int j = 0; j < 16; ++j) p[j] = xx[t + j] * ee[t + j];
        S0 = p[0] + (p[4] + (p[8]  + (p[12] + S0)));
        S1 = p[1] + (p[5] + (p[9]  + (p[13] + S1)));
        S2 = p[2] + (p[6] + (p[10] + (p[14] + S2)));
        S3 = p[3] + (p[7] + (p[11] + (p[15] + S3)));
    }
    return (S0 + S1) + (S2 + S3);
}

// ---- prep: np-exact e2; Eh(fp16,x64) fragment layout; m2bf(-32*e2) ---------
// Block = 32 codes, 8 threads/code (t: piece p=t>>5, code cw=t&31).
// uint4 units: [((pair*64+gg)*8 + piece)*32 + cc], pair=h*2+half, gg=(c&2047)>>5.
__global__ __launch_bounds__(256) void prep_ke(const float* __restrict__ ke,
                                               uint4* __restrict__ EhT,
                                               float* __restrict__ e2np,
                                               unsigned short* __restrict__ m2bf,
                                               int* __restrict__ wl_count) {
    __shared__ float sq[32][64];
    __shared__ float rr[32][8];
    const int t = threadIdx.x;
    if (blockIdx.x == 0 && t < 2) wl_count[t] = 0;
    const int p = t >> 5, cw = t & 31;
    const int idx = blockIdx.x * 32 + cw;          // all 32 codes share h/half/gg

    float er[8];
    {
        const float4* p4 = reinterpret_cast<const float4*>(
            ke + (size_t)idx * DKI + p * 8);
        float4 v0 = p4[0], v1 = p4[1];
        er[0] = v0.x; er[1] = v0.y; er[2] = v0.z; er[3] = v0.w;
        er[4] = v1.x; er[5] = v1.y; er[6] = v1.z; er[7] = v1.w;
    }
    {
#pragma clang fp contract(off)
#pragma unroll
        for (int j = 0; j < 8; ++j) sq[cw][p * 8 + j] = er[j] * er[j];
    }
    __syncthreads();
    {   // residue chain rho = p : r = ((sq[rho]+sq[8+rho])+sq[16+rho])+...
#pragma clang fp contract(off)
        float r = sq[cw][p];
#pragma unroll
        for (int k = 1; k < 8; ++k) r = r + sq[cw][k * 8 + p];
        rr[cw][p] = r;
    }
    __syncthreads();
    const int h = idx >> 12, c = idx & 4095;
    const int half = c >> 11, gg = (c & 2047) >> 5;
    const int pair = h * 2 + half;
    if (p == 0) {
#pragma clang fp contract(off)
        float e2 = ((rr[cw][0] + rr[cw][1]) + (rr[cw][2] + rr[cw][3])) +
                   ((rr[cw][4] + rr[cw][5]) + (rr[cw][6] + rr[cw][7]));
        e2np[idx] = e2;
        m2bf[(size_t)pair * 2048 + (c & 2047)] = f2bf(-32.f * e2);
    }

    unsigned int hb[8];
#pragma unroll
    for (int j = 0; j < 8; ++j)
        hb[j] = f2h(er[j] * 64.f);                 // exact pow2 scale
    uint4 hv;
    hv.x = hb[0] | (hb[1] << 16); hv.y = hb[2] | (hb[3] << 16);
    hv.z = hb[4] | (hb[5] << 16); hv.w = hb[6] | (hb[7] << 16);
    EhT[((size_t)(pair * 64 + gg) * 8 + p) * 32 + cw] = hv;
}

// sorted-triple merge network (tie -> first/left operand)
#define MERGE3(v1o, i1o, v2o, i2o, v3o,                                   \
               a1, j1, a2, j2, a3, b1, k1, b2, k2, b3)                    \
    {                                                                     \
        bool t1 = (b1) > (a1);                                            \
        float _l1 = t1 ? (a1) : (b1);  int _k1 = t1 ? (j1) : (k1);        \
        (v1o) = t1 ? (b1) : (a1);      (i1o) = t1 ? (k1) : (j1);          \
        float _s2 = t1 ? (b2) : (a2);  int _u2 = t1 ? (k2) : (j2);        \
        bool t2 = _s2 > _l1;                                              \
        (v2o) = t2 ? _s2 : _l1;        (i2o) = t2 ? _u2 : _k1;            \
        float _l2 = t2 ? _l1 : _s2;                                       \
        float _s3 = t2 ? (t1 ? (b3) : (a3)) : (t1 ? (a2) : (b2));         \
        bool t3 = _s3 > _l2;                                              \
        (v3o) = t3 ? _s3 : _l2;                                           \
    }

// ---- pass 1: fp16-only MFMA, reg staging, 32q x quarter waves --------------
// grid 1536 = 12 heads x 128 q-blocks (h=b%12). Block: 4 waves, 32 queries,
// full codebook; wave w covers codes [w*1024,(w+1)*1024) in 32 chunks of 32.
__global__ __launch_bounds__(256, 4) void dkvb_pass1(
        const float* __restrict__ x,
        const char* __restrict__ EhT,
        const unsigned short* __restrict__ m2bf,
        const float* __restrict__ values,
        int* __restrict__ wl_count,
        int* __restrict__ wl,
        int* __restrict__ wlc,
        int* __restrict__ wlf,
        unsigned long long* __restrict__ res,
        float* __restrict__ out) {
    __shared__ float sb1[4][32], sb2[4][32], sb3[4][32];
    __shared__ int   sbi[4][32];
    __shared__ int   fin[32];

    const int tid  = threadIdx.x;
    const int h    = blockIdx.x % 12;
    const int qb   = blockIdx.x / 12;
    const int w    = tid >> 6;               // code quarter
    const int lane = tid & 63;
    const int col  = lane & 31;              // B col (code) / A row (query)
    const int kh   = lane >> 5;              // k-half within K=16 step
    const int q0   = qb * 32;
    const int pair = h * 2 + (w >> 1);

    // ---- A fragments (fp16): query m = q0+col; k = t*16 + kh*8 + j
    const float* xrow = x + (size_t)(q0 + col) * DIMX + h * DKI;
    f16x8 ah[4];
#pragma unroll
    for (int t = 0; t < 4; ++t) {
        const float* p = xrow + t * 16 + kh * 8;
        float4 v0 = *reinterpret_cast<const float4*>(p);
        float4 v1 = *reinterpret_cast<const float4*>(p + 4);
        f16x8 hv;
        hv[0] = (_Float16)v0.x; hv[1] = (_Float16)v0.y;
        hv[2] = (_Float16)v0.z; hv[3] = (_Float16)v0.w;
        hv[4] = (_Float16)v1.x; hv[5] = (_Float16)v1.y;
        hv[6] = (_Float16)v1.z; hv[7] = (_Float16)v1.w;
        ah[t] = hv;
    }
    // m2 A-side const fragment: k=0 slot = 1.0bf16 (kh=0 lanes only)
    const bf16x8 am2 = (bf16x8){(short)(kh ? 0 : 0x3F80), 0, 0, 0, 0, 0, 0, 0};

    const char* gE = EhT + (size_t)pair * 262144 + (size_t)(w & 1) * 131072
                   + (size_t)kh * 512 + (size_t)col * 16;
    const unsigned short* gm = m2bf + (size_t)pair * 2048
                             + (size_t)(w & 1) * 1024 + col;

    f32x16 zacc;
#pragma unroll
    for (int r = 0; r < 16; ++r) zacc[r] = 0.f;

    float bv[16], bv2[16], bv3[16];
#pragma unroll
    for (int r = 0; r < 16; ++r) { bv[r] = -1e30f; bv2[r] = -1e30f; bv3[r] = -1e30f; }

    auto LOADF = [&](int i, uint4& e0, uint4& e1, uint4& e2, uint4& e3,
                     unsigned short& mA) {
        const char* p = gE + (size_t)i * 4096;
        e0 = *reinterpret_cast<const uint4*>(p);
        e1 = *reinterpret_cast<const uint4*>(p + 1024);
        e2 = *reinterpret_cast<const uint4*>(p + 2048);
        e3 = *reinterpret_cast<const uint4*>(p + 3072);
        mA = gm[i * 32];
    };
    auto COMPUTE = [&](int i, uint4 e0, uint4 e1, uint4 e2, uint4 e3,
                       unsigned short mA) {
        bf16x8 bm = (bf16x8){(short)(kh ? 0 : mA), 0, 0, 0, 0, 0, 0, 0};
        f32x16 acc;
        acc = __builtin_amdgcn_mfma_f32_32x32x16_bf16(am2,   bm,          zacc, 0, 0, 0);
        acc = __builtin_amdgcn_mfma_f32_32x32x16_f16 (ah[0], as_f16x8(e0), acc, 0, 0, 0);
        acc = __builtin_amdgcn_mfma_f32_32x32x16_f16 (ah[1], as_f16x8(e1), acc, 0, 0, 0);
        acc = __builtin_amdgcn_mfma_f32_32x32x16_f16 (ah[2], as_f16x8(e2), acc, 0, 0, 0);
        acc = __builtin_amdgcn_mfma_f32_32x32x16_f16 (ah[3], as_f16x8(e3), acc, 0, 0, 0);
        unsigned enc = (unsigned)i;          // chunk id in mantissa LSBs
#pragma unroll
        for (int r = 0; r < 16; ++r) {
            float sp = __uint_as_float(
                (__float_as_uint(acc[r]) & 0xFFFFFFC0u) | enc);
            bv3[r] = __builtin_amdgcn_fmed3f(bv3[r], sp, bv2[r]);  // old v2
            bv2[r] = __builtin_amdgcn_fmed3f(bv2[r], sp, bv[r]);   // old v1
            bv[r]  = fmaxf(bv[r], sp);
        }
    };

    uint4 A0, A1, A2, A3, B0, B1, B2, B3;
    unsigned short Am, Bm;
    LOADF(0, A0, A1, A2, A3, Am);
#pragma unroll 1
    for (int i = 0; i < 32; i += 2) {        // named-reg dbuf, static indexing
        LOADF(i + 1, B0, B1, B2, B3, Bm);
        COMPUTE(i, A0, A1, A2, A3, Am);
        if (i + 2 < 32) LOADF(i + 2, A0, A1, A2, A3, Am);
        COMPUTE(i + 1, B0, B1, B2, B3, Bm);
    }

    // ---- decode packed indices (global code id), cross-col butterfly -------
    int bi1[16], bi2[16];
#pragma unroll
    for (int r = 0; r < 16; ++r) {
        bi1[r] = (int)(__float_as_uint(bv[r])  & 63u) * 32 + col + w * 1024;
        bi2[r] = (int)(__float_as_uint(bv2[r]) & 63u) * 32 + col + w * 1024;
    }
#pragma unroll
    for (int r = 0; r < 16; ++r) {
#pragma unroll
        for (int m = 1; m <= 16; m <<= 1) {
            float p1 = __shfl_xor(bv[r],  m, 64);
            float p2 = __shfl_xor(bv2[r], m, 64);
            float p3 = __shfl_xor(bv3[r], m, 64);
            int   q1 = __shfl_xor(bi1[r], m, 64);
            int   q2 = __shfl_xor(bi2[r], m, 64);
            bool t1 = (p1 > bv[r]) || (p1 == bv[r] && q1 < bi1[r]);
            float w1 = t1 ? p1 : bv[r];   int j1 = t1 ? q1 : bi1[r];
            float l1 = t1 ? bv[r] : p1;   int k1 = t1 ? bi1[r] : q1;
            float s2 = t1 ? p2 : bv2[r];  int u2 = t1 ? q2 : bi2[r];
            bool t2 = s2 > l1;
            float w2 = t2 ? s2 : l1;      int j2 = t2 ? u2 : k1;
            float l2 = t2 ? l1 : s2;
            float s3 = t2 ? (t1 ? p3 : bv3[r]) : (t1 ? bv2[r] : p2);
            bool t3 = s3 > l2;
            float w3 = t3 ? s3 : l2;
            bv[r] = w1; bi1[r] = j1;
            bv2[r] = w2; bi2[r] = j2;
            bv3[r] = w3;
        }
    }
    if (col == 0) {                          // lanes 0 and 32, disjoint rows
#pragma unroll
        for (int r = 0; r < 16; ++r) {
            int row = (r & 3) + 8 * (r >> 2) + 4 * kh;   // 0..31
            sb1[w][row] = bv[r];
            sb2[w][row] = bv2[r];
            sb3[w][row] = bv3[r];
            sbi[w][row] = (bi1[r] << 16) | bi2[r];
        }
    }
    __syncthreads();

    // ---- 4-way quarter merge, flag, route worklists ------------------------
    if (tid < 32) {
        float v1[4], v2[4], v3[4]; int i1[4], i2[4];
#pragma unroll
        for (int qd = 0; qd < 4; ++qd) {
            v1[qd] = sb1[qd][tid]; v2[qd] = sb2[qd][tid]; v3[qd] = sb3[qd][tid];
            int pk = sbi[qd][tid];
            i1[qd] = (pk >> 16) & 0xffff; i2[qd] = pk & 0xffff;
        }
        float m1a, m2a, m3a, m1b, m2b, m3b, V1, V2, V3;
        int j1a, j2a, j1b, j2b, I1, I2;
        MERGE3(m1a, j1a, m2a, j2a, m3a,
               v1[0], i1[0], v2[0], i2[0], v3[0],
               v1[1], i1[1], v2[1], i2[1], v3[1]);
        MERGE3(m1b, j1b, m2b, j2b, m3b,
               v1[2], i1[2], v2[2], i2[2], v3[2],
               v1[3], i1[3], v2[3], i2[3], v3[3]);
        MERGE3(V1, I1, V2, I2, V3,
               m1a, j1a, m2a, j2a, m3a,
               m1b, j1b, m2b, j2b, m3b);
        fin[tid] = I1;
        if (V1 - V2 < TAUS) {
            if (V1 - V3 < TAUS) {            // near-tie: full np rescan
                int slot = atomicAdd(wl_count + 1, 1);
                if (slot < WLCAP) {
                    wlf[slot] = (h << 16) | (q0 + tid);
                    res[slot] = ~0ULL;
                }
            } else {                         // provable 2-candidate set
                int slot = atomicAdd(wl_count, 1);
                if (slot < WLCAP) {
                    wl[slot]  = (h << 16) | (q0 + tid);
                    wlc[slot] = (I1 << 16) | I2;
                }
            }
        }
    }
    __syncthreads();

    // ---- gather values[h, fin[q], :] -> out; 32 rows x 16 float4 -----------
#pragma unroll
    for (int k = 0; k < 2; ++k) {
        int f   = tid + k * 256;
        int row = f >> 4;
        int cl  = (f & 15) << 2;
        int idx = fin[row];
        float4 v = *reinterpret_cast<const float4*>(
            values + (size_t)h * CODES * DVI + (size_t)idx * DVI + cl);
        *reinterpret_cast<float4*>(
            out + (size_t)(q0 + row) * DIMX + h * DVI + cl) = v;
    }
}

// ---- pass 2a: np-exact 2-candidate check, one wave per flagged entry -------
__global__ __launch_bounds__(256) void cand_check(const float* __restrict__ x,
                                                  const float* __restrict__ ke,
                                                  const float* __restrict__ e2np,
                                                  const float* __restrict__ values,
                                                  const int* __restrict__ wl_count,
                                                  const int* __restrict__ wl,
                                                  const int* __restrict__ wlc,
                                                  float* __restrict__ out) {
    __shared__ float xs[4][DKI];
    const int t = threadIdx.x, w = t >> 6, lane = t & 63;
    int cnt = wl_count[0];
    if (cnt > WLCAP) cnt = WLCAP;

    for (int e = blockIdx.x * 4 + w; e < cnt; e += gridDim.x * 4) {
        int ent = wl[e];
        int h = ent >> 16, nq = ent & 0xffff;
        int cp = wlc[e];
        if (lane < 16) {
            float4 v = *reinterpret_cast<const float4*>(
                x + (size_t)nq * DIMX + h * DKI + lane * 4);
            *reinterpret_cast<float4*>(&xs[w][lane * 4]) = v;
        }
        asm volatile("s_waitcnt lgkmcnt(0)" ::: "memory");
        __builtin_amdgcn_sched_barrier(0);

        int i1 = (cp >> 16) & 0xffff, i2 = cp & 0xffff;
        float d2 = 0.f;
        if (lane < 2) {
            int myc = lane ? i2 : i1;
            float er[DKI];
            const float4* p = reinterpret_cast<const float4*>(
                ke + ((size_t)h * CODES + myc) * DKI);
#pragma unroll
            for (int i = 0; i < DKI / 4; ++i) {
                float4 v = p[i];
                er[i * 4 + 0] = v.x; er[i * 4 + 1] = v.y;
                er[i * 4 + 2] = v.z; er[i * 4 + 3] = v.w;
            }
            float x2 = np_sumsq64(xs[w]);
            float dot = np_dot64(xs[w], er);
            {
#pragma clang fp contract(off)
                d2 = (x2 - 2.0f * dot) + e2np[h * CODES + myc];
            }
        }
        float dA = __shfl(d2, 0, 64);
        float dB = __shfl(d2, 1, 64);
        int win = (dB < dA || (dB == dA && i2 < i1)) ? i2 : i1;
        if (lane < 16) {
            float4 v = *reinterpret_cast<const float4*>(
                values + ((size_t)h * CODES + win) * DVI + lane * 4);
            *reinterpret_cast<float4*>(
                out + (size_t)nq * DIMX + h * DVI + lane * 4) = v;
        }
    }
}

// ---- pass 2b: np-exact full rescan for near-ties, wave per (entry, 1/8) ----
__global__ __launch_bounds__(256) void np_full(const float* __restrict__ x,
                                               const float* __restrict__ ke,
                                               const float* __restrict__ e2np,
                                               const int* __restrict__ wl_count,
                                               const int* __restrict__ wlf,
                                               unsigned long long* __restrict__ res) {
    __shared__ float xs[4][DKI];
    const int t = threadIdx.x, w = t >> 6, lane = t & 63;
    int cnt = wl_count[1];
    if (cnt > WLCAP) cnt = WLCAP;
    const int total = cnt * 8;

    for (int wk = blockIdx.x * 4 + w; wk < total; wk += gridDim.x * 4) {
        const int e = wk >> 3, part = wk & 7;
        const int ent = wlf[e];
        const int h = ent >> 16, nq = ent & 0xffff;
        if (lane < 16) {
            float4 v = *reinterpret_cast<const float4*>(
                x + (size_t)nq * DIMX + h * DKI + lane * 4);
            *reinterpret_cast<float4*>(&xs[w][lane * 4]) = v;
        }
        asm volatile("s_waitcnt lgkmcnt(0)" ::: "memory");
        __builtin_amdgcn_sched_barrier(0);

        float x2 = np_sumsq64(xs[w]);
        unsigned long long best = ~0ULL;
#pragma unroll 1
        for (int it = 0; it < 8; ++it) {
            int c = part * 512 + it * 64 + lane;
            float er[DKI];
            const float4* p = reinterpret_cast<const float4*>(
                ke + ((size_t)h * CODES + c) * DKI);
#pragma unroll
            for (int i = 0; i < DKI / 4; ++i) {
                float4 v = p[i];
                er[i * 4 + 0] = v.x; er[i * 4 + 1] = v.y;
                er[i * 4 + 2] = v.z; er[i * 4 + 3] = v.w;
            }
            float dot = np_dot64(xs[w], er);
            float d2;
            {
#pragma clang fp contract(off)
                d2 = (x2 - 2.0f * dot) + e2np[h * CODES + c];
            }
            unsigned u = __float_as_uint(d2);
            unsigned key = (u & 0x80000000u) ? ~u : (u | 0x80000000u);
            unsigned long long pk = ((unsigned long long)key << 32) | (unsigned)c;
            best = pk < best ? pk : best;
        }
#pragma unroll
        for (int m = 1; m <= 32; m <<= 1) {
            unsigned long long o =
                (unsigned long long)__shfl_xor((long long)best, m, 64);
            best = o < best ? o : best;
        }
        if (lane == 0) atomicMin(res + e, best);
    }
}

// ---- pass 2c: write near-tie winners ---------------------------------------
__global__ __launch_bounds__(256) void np_fin(const float* __restrict__ values,
                                              const int* __restrict__ wl_count,
                                              const int* __restrict__ wlf,
                                              const unsigned long long* __restrict__ res,
                                              float* __restrict__ out) {
    int cnt = wl_count[1];
    if (cnt > WLCAP) cnt = WLCAP;
    const int total = cnt * 16;              // 16 float4 per entry
    for (int f = blockIdx.x * 256 + threadIdx.x; f < total; f += gridDim.x * 256) {
        int e  = f >> 4;
        int cl = (f & 15) << 2;
        int ent = wlf[e];
        int h = ent >> 16, nq = ent & 0xffff;
        int c = (int)(res[e] & 0xFFFFFFFFULL);
        float4 v = *reinterpret_cast<const float4*>(
            values + ((size_t)h * CODES + c) * DVI + cl);
        *reinterpret_cast<float4*>(
            out + (size_t)nq * DIMX + h * DVI + cl) = v;
    }
}

extern "C" void kernel_launch(void* const* d_in, const int* in_sizes, int n_in,
                              void* d_out, int out_size, void* d_ws, size_t ws_size,
                              hipStream_t stream) {
    const float* x      = (const float*)d_in[0];
    // d_in[1] = mask (all ones; unused)
    const float* ke     = (const float*)d_in[2];
    const float* values = (const float*)d_in[3];
    // d_in[4] = key_optim (unused)
    float* out = (float*)d_out;

    char* ws = (char*)d_ws;
    float* e2np          = (float*)ws;          ws += (size_t)HEADS * CODES * 4;      // 196608
    unsigned short* m2bf = (unsigned short*)ws; ws += (size_t)HEADS * 2 * 2048 * 2;   // 98304
    int*   wl_count      = (int*)ws;            ws += 64;
    int*   wl            = (int*)ws;            ws += (size_t)WLCAP * 4;              // 131072
    int*   wlc           = (int*)ws;            ws += (size_t)WLCAP * 4;              // 131072
    int*   wlf           = (int*)ws;            ws += (size_t)WLCAP * 4;              // 131072
    unsigned long long* res = (unsigned long long*)ws; ws += (size_t)WLCAP * 8;       // 262144
    char*  EhT           = ws;                  ws += (size_t)HEADS * CODES * 128;    // 6291456

    prep_ke<<<dim3(HEADS * CODES / 32), dim3(256), 0, stream>>>(
        ke, (uint4*)EhT, e2np, m2bf, wl_count);
    dkvb_pass1<<<dim3(1536), dim3(256), 0, stream>>>(
        x, EhT, m2bf, values, wl_count, wl, wlc, wlf, res, out);
    cand_check<<<dim3(1024), dim3(256), 0, stream>>>(
        x, ke, e2np, values, wl_count, wl, wlc, out);
    np_full<<<dim3(1024), dim3(256), 0, stream>>>(
        x, ke, e2np, wl_count, wlf, res);
    np_fin<<<dim3(256), dim3(256), 0, stream>>>(
        values, wl_count, wlf, res, out);
}

// Round 7
// 192.566 us; speedup vs baseline: 1.3610x; 1.0276x over previous
//
#include <hip/hip_runtime.h>

// DiscreteKeyValueBottleneck on MI355X (gfx950)
// B=4 T=1024 H=12 C=4096 DK=DV=64, N=B*T=4096, DIM=768
//
// Round 13: r6's pass1 regression was SPILL-induced (launch_bounds(256,4)
// capped regs at 128 < ~140 live set: VGPR 80->64, FETCH 17->57MB,
// WRITE 12->72MB = scratch traffic). Changes:
//  * pass1: __launch_bounds__(256,3) (cap ~170, r5-proven, no spill),
//    grid 1536 kept; staging deepened to 3 named buffers, step-3 rotation
//    (prefetch distance 2, ~500cyc L2 latency covered, zero guards).
//  * post kernels fused into ONE post_check: items = cnt0 2-cand entries
//    + cnt1*8 near-tie parts; parts merge via packed-key atomicMin with
//    threadfence-ordered completion counter; last part writes out.
//    6 launches -> 3.
//  * fp16-only scores, m2-in-MFMA, packed-mantissa top-3, quarter waves,
//    TAU 1.2e-4 -- unchanged from r12.

#define HEADS 12
#define CODES 4096
#define DKI   64
#define DVI   64
#define DIMX  768
#define TAUS  7.68e-3f    // 64 * 1.2e-4 (scores carry the x64 E-scale)
#define WLCAP 32768

typedef short bf16x8 __attribute__((ext_vector_type(8)));
typedef _Float16 f16x8 __attribute__((ext_vector_type(8)));
typedef float f32x16 __attribute__((ext_vector_type(16)));

__device__ __forceinline__ unsigned short f2bf(float f) {   // RNE
    unsigned int u = __float_as_uint(f);
    return (unsigned short)((u + 0x7fff + ((u >> 16) & 1)) >> 16);
}
__device__ __forceinline__ unsigned short f2h(float f) {    // RNE f32->f16
    _Float16 h = (_Float16)f;
    unsigned short u;
    __builtin_memcpy(&u, &h, 2);
    return u;
}
__device__ __forceinline__ f16x8 as_f16x8(uint4 v) {
    union { uint4 u; f16x8 h; } c; c.u = v; return c.h;
}

// ---------------- numpy bit-exact helpers (fp32, contraction OFF) -----------
__device__ __forceinline__ float np_sumsq64(const float* __restrict__ a) {
#pragma clang fp contract(off)
    float r[8];
#pragma unroll
    for (int j = 0; j < 8; ++j) r[j] = a[j] * a[j];
#pragma unroll
    for (int i = 8; i < 64; i += 8)
#pragma unroll
        for (int j = 0; j < 8; ++j) r[j] += a[i + j] * a[i + j];
    return ((r[0] + r[1]) + (r[2] + r[3])) + ((r[4] + r[5]) + (r[6] + r[7]));
}

__device__ __forceinline__ float np_dot64(const float* __restrict__ xx,
                                          const float* __restrict__ ee) {
#pragma clang fp contract(off)
    float S0 = 0.f, S1 = 0.f, S2 = 0.f, S3 = 0.f;
#pragma unroll
    for (int t = 0; t < 64; t += 16) {
        float p[16];
#pragma unroll
        for (int j = 0; j < 16; ++j) p[j] = xx[t + j] * ee[t + j];
        S0 = p[0] + (p[4] + (p[8]  + (p[12] + S0)));
        S1 = p[1] + (p[5] + (p[9]  + (p[13] + S1)));
        S2 = p[2] + (p[6] + (p[10] + (p[14] + S2)));
        S3 = p[3] + (p[7] + (p[11] + (p[15] + S3)));
    }
    return (S0 + S1) + (S2 + S3);
}

// ---- prep: np-exact e2; Eh(fp16,x64) fragment layout; m2bf(-32*e2) ---------
// Block = 32 codes, 8 threads/code (t: piece p=t>>5, code cw=t&31).
// uint4 units: [((pair*64+gg)*8 + piece)*32 + cc], pair=h*2+half, gg=(c&2047)>>5.
__global__ __launch_bounds__(256) void prep_ke(const float* __restrict__ ke,
                                               uint4* __restrict__ EhT,
                                               float* __restrict__ e2np,
                                               unsigned short* __restrict__ m2bf,
                                               int* __restrict__ wl_count) {
    __shared__ float sq[32][64];
    __shared__ float rr[32][8];
    const int t = threadIdx.x;
    if (blockIdx.x == 0 && t < 2) wl_count[t] = 0;
    const int p = t >> 5, cw = t & 31;
    const int idx = blockIdx.x * 32 + cw;          // all 32 codes share h/half/gg

    float er[8];
    {
        const float4* p4 = reinterpret_cast<const float4*>(
            ke + (size_t)idx * DKI + p * 8);
        float4 v0 = p4[0], v1 = p4[1];
        er[0] = v0.x; er[1] = v0.y; er[2] = v0.z; er[3] = v0.w;
        er[4] = v1.x; er[5] = v1.y; er[6] = v1.z; er[7] = v1.w;
    }
    {
#pragma clang fp contract(off)
#pragma unroll
        for (int j = 0; j < 8; ++j) sq[cw][p * 8 + j] = er[j] * er[j];
    }
    __syncthreads();
    {   // residue chain rho = p : r = ((sq[rho]+sq[8+rho])+sq[16+rho])+...
#pragma clang fp contract(off)
        float r = sq[cw][p];
#pragma unroll
        for (int k = 1; k < 8; ++k) r = r + sq[cw][k * 8 + p];
        rr[cw][p] = r;
    }
    __syncthreads();
    const int h = idx >> 12, c = idx & 4095;
    const int half = c >> 11, gg = (c & 2047) >> 5;
    const int pair = h * 2 + half;
    if (p == 0) {
#pragma clang fp contract(off)
        float e2 = ((rr[cw][0] + rr[cw][1]) + (rr[cw][2] + rr[cw][3])) +
                   ((rr[cw][4] + rr[cw][5]) + (rr[cw][6] + rr[cw][7]));
        e2np[idx] = e2;
        m2bf[(size_t)pair * 2048 + (c & 2047)] = f2bf(-32.f * e2);
    }

    unsigned int hb[8];
#pragma unroll
    for (int j = 0; j < 8; ++j)
        hb[j] = f2h(er[j] * 64.f);                 // exact pow2 scale
    uint4 hv;
    hv.x = hb[0] | (hb[1] << 16); hv.y = hb[2] | (hb[3] << 16);
    hv.z = hb[4] | (hb[5] << 16); hv.w = hb[6] | (hb[7] << 16);
    EhT[((size_t)(pair * 64 + gg) * 8 + p) * 32 + cw] = hv;
}

// sorted-triple merge network (tie -> first/left operand)
#define MERGE3(v1o, i1o, v2o, i2o, v3o,                                   \
               a1, j1, a2, j2, a3, b1, k1, b2, k2, b3)                    \
    {                                                                     \
        bool t1 = (b1) > (a1);                                            \
        float _l1 = t1 ? (a1) : (b1);  int _k1 = t1 ? (j1) : (k1);        \
        (v1o) = t1 ? (b1) : (a1);      (i1o) = t1 ? (k1) : (j1);          \
        float _s2 = t1 ? (b2) : (a2);  int _u2 = t1 ? (k2) : (j2);        \
        bool t2 = _s2 > _l1;                                              \
        (v2o) = t2 ? _s2 : _l1;        (i2o) = t2 ? _u2 : _k1;            \
        float _l2 = t2 ? _l1 : _s2;                                       \
        float _s3 = t2 ? (t1 ? (b3) : (a3)) : (t1 ? (a2) : (b2));         \
        bool t3 = _s3 > _l2;                                              \
        (v3o) = t3 ? _s3 : _l2;                                           \
    }

// ---- pass 1: fp16-only MFMA, 3-buffer reg staging, 32q x quarter waves -----
// grid 1536 = 12 heads x 128 q-blocks (h=b%12). Block: 4 waves, 32 queries,
// full codebook; wave w covers codes [w*1024,(w+1)*1024) in 32 chunks of 32.
__global__ __launch_bounds__(256, 3) void dkvb_pass1(
        const float* __restrict__ x,
        const char* __restrict__ EhT,
        const unsigned short* __restrict__ m2bf,
        const float* __restrict__ values,
        int* __restrict__ wl_count,
        int* __restrict__ wl,
        int* __restrict__ wlc,
        int* __restrict__ wlf,
        unsigned long long* __restrict__ res,
        int* __restrict__ pcnt,
        float* __restrict__ out) {
    __shared__ float sb1[4][32], sb2[4][32], sb3[4][32];
    __shared__ int   sbi[4][32];
    __shared__ int   fin[32];

    const int tid  = threadIdx.x;
    const int h    = blockIdx.x % 12;
    const int qb   = blockIdx.x / 12;
    const int w    = tid >> 6;               // code quarter
    const int lane = tid & 63;
    const int col  = lane & 31;              // B col (code) / A row (query)
    const int kh   = lane >> 5;              // k-half within K=16 step
    const int q0   = qb * 32;
    const int pair = h * 2 + (w >> 1);

    // ---- A fragments (fp16): query m = q0+col; k = t*16 + kh*8 + j
    const float* xrow = x + (size_t)(q0 + col) * DIMX + h * DKI;
    f16x8 ah[4];
#pragma unroll
    for (int t = 0; t < 4; ++t) {
        const float* p = xrow + t * 16 + kh * 8;
        float4 v0 = *reinterpret_cast<const float4*>(p);
        float4 v1 = *reinterpret_cast<const float4*>(p + 4);
        f16x8 hv;
        hv[0] = (_Float16)v0.x; hv[1] = (_Float16)v0.y;
        hv[2] = (_Float16)v0.z; hv[3] = (_Float16)v0.w;
        hv[4] = (_Float16)v1.x; hv[5] = (_Float16)v1.y;
        hv[6] = (_Float16)v1.z; hv[7] = (_Float16)v1.w;
        ah[t] = hv;
    }
    // m2 A-side const fragment: k=0 slot = 1.0bf16 (kh=0 lanes only)
    const bf16x8 am2 = (bf16x8){(short)(kh ? 0 : 0x3F80), 0, 0, 0, 0, 0, 0, 0};

    const char* gE = EhT + (size_t)pair * 262144 + (size_t)(w & 1) * 131072
                   + (size_t)kh * 512 + (size_t)col * 16;
    const unsigned short* gm = m2bf + (size_t)pair * 2048
                             + (size_t)(w & 1) * 1024 + col;

    f32x16 zacc;
#pragma unroll
    for (int r = 0; r < 16; ++r) zacc[r] = 0.f;

    float bv[16], bv2[16], bv3[16];
#pragma unroll
    for (int r = 0; r < 16; ++r) { bv[r] = -1e30f; bv2[r] = -1e30f; bv3[r] = -1e30f; }

    auto LOADF = [&](int i, uint4& e0, uint4& e1, uint4& e2, uint4& e3,
                     unsigned short& mA) {
        const char* p = gE + (size_t)i * 4096;
        e0 = *reinterpret_cast<const uint4*>(p);
        e1 = *reinterpret_cast<const uint4*>(p + 1024);
        e2 = *reinterpret_cast<const uint4*>(p + 2048);
        e3 = *reinterpret_cast<const uint4*>(p + 3072);
        mA = gm[i * 32];
    };
    auto COMPUTE = [&](int i, uint4 e0, uint4 e1, uint4 e2, uint4 e3,
                       unsigned short mA) {
        bf16x8 bm = (bf16x8){(short)(kh ? 0 : mA), 0, 0, 0, 0, 0, 0, 0};
        f32x16 acc;
        acc = __builtin_amdgcn_mfma_f32_32x32x16_bf16(am2,   bm,          zacc, 0, 0, 0);
        acc = __builtin_amdgcn_mfma_f32_32x32x16_f16 (ah[0], as_f16x8(e0), acc, 0, 0, 0);
        acc = __builtin_amdgcn_mfma_f32_32x32x16_f16 (ah[1], as_f16x8(e1), acc, 0, 0, 0);
        acc = __builtin_amdgcn_mfma_f32_32x32x16_f16 (ah[2], as_f16x8(e2), acc, 0, 0, 0);
        acc = __builtin_amdgcn_mfma_f32_32x32x16_f16 (ah[3], as_f16x8(e3), acc, 0, 0, 0);
        unsigned enc = (unsigned)i;          // chunk id in mantissa LSBs
#pragma unroll
        for (int r = 0; r < 16; ++r) {
            float sp = __uint_as_float(
                (__float_as_uint(acc[r]) & 0xFFFFFFC0u) | enc);
            bv3[r] = __builtin_amdgcn_fmed3f(bv3[r], sp, bv2[r]);  // old v2
            bv2[r] = __builtin_amdgcn_fmed3f(bv2[r], sp, bv[r]);   // old v1
            bv[r]  = fmaxf(bv[r], sp);
        }
    };

    // 3-buffer rotation, prefetch distance 2, fully static names, no guards
    uint4 A0, A1, A2, A3, B0, B1, B2, B3, C0, C1, C2, C3;
    unsigned short Am, Bm, Cm;
    LOADF(0, A0, A1, A2, A3, Am);
    LOADF(1, B0, B1, B2, B3, Bm);
#pragma unroll 1
    for (int i = 0; i < 30; i += 3) {
        LOADF(i + 2, C0, C1, C2, C3, Cm);
        COMPUTE(i, A0, A1, A2, A3, Am);
        LOADF(i + 3, A0, A1, A2, A3, Am);
        COMPUTE(i + 1, B0, B1, B2, B3, Bm);
        LOADF(i + 4, B0, B1, B2, B3, Bm);
        COMPUTE(i + 2, C0, C1, C2, C3, Cm);
    }
    COMPUTE(30, A0, A1, A2, A3, Am);
    COMPUTE(31, B0, B1, B2, B3, Bm);

    // ---- decode packed indices (global code id), cross-col butterfly -------
    int bi1[16], bi2[16];
#pragma unroll
    for (int r = 0; r < 16; ++r) {
        bi1[r] = (int)(__float_as_uint(bv[r])  & 63u) * 32 + col + w * 1024;
        bi2[r] = (int)(__float_as_uint(bv2[r]) & 63u) * 32 + col + w * 1024;
    }
#pragma unroll
    for (int r = 0; r < 16; ++r) {
#pragma unroll
        for (int m = 1; m <= 16; m <<= 1) {
            float p1 = __shfl_xor(bv[r],  m, 64);
            float p2 = __shfl_xor(bv2[r], m, 64);
            float p3 = __shfl_xor(bv3[r], m, 64);
            int   q1 = __shfl_xor(bi1[r], m, 64);
            int   q2 = __shfl_xor(bi2[r], m, 64);
            bool t1 = (p1 > bv[r]) || (p1 == bv[r] && q1 < bi1[r]);
            float w1 = t1 ? p1 : bv[r];   int j1 = t1 ? q1 : bi1[r];
            float l1 = t1 ? bv[r] : p1;   int k1 = t1 ? bi1[r] : q1;
            float s2 = t1 ? p2 : bv2[r];  int u2 = t1 ? q2 : bi2[r];
            bool t2 = s2 > l1;
            float w2 = t2 ? s2 : l1;      int j2 = t2 ? u2 : k1;
            float l2 = t2 ? l1 : s2;
            float s3 = t2 ? (t1 ? p3 : bv3[r]) : (t1 ? bv2[r] : p2);
            bool t3 = s3 > l2;
            float w3 = t3 ? s3 : l2;
            bv[r] = w1; bi1[r] = j1;
            bv2[r] = w2; bi2[r] = j2;
            bv3[r] = w3;
        }
    }
    if (col == 0) {                          // lanes 0 and 32, disjoint rows
#pragma unroll
        for (int r = 0; r < 16; ++r) {
            int row = (r & 3) + 8 * (r >> 2) + 4 * kh;   // 0..31
            sb1[w][row] = bv[r];
            sb2[w][row] = bv2[r];
            sb3[w][row] = bv3[r];
            sbi[w][row] = (bi1[r] << 16) | bi2[r];
        }
    }
    __syncthreads();

    // ---- 4-way quarter merge, flag, route worklists ------------------------
    if (tid < 32) {
        float v1[4], v2[4], v3[4]; int i1[4], i2[4];
#pragma unroll
        for (int qd = 0; qd < 4; ++qd) {
            v1[qd] = sb1[qd][tid]; v2[qd] = sb2[qd][tid]; v3[qd] = sb3[qd][tid];
            int pk = sbi[qd][tid];
            i1[qd] = (pk >> 16) & 0xffff; i2[qd] = pk & 0xffff;
        }
        float m1a, m2a, m3a, m1b, m2b, m3b, V1, V2, V3;
        int j1a, j2a, j1b, j2b, I1, I2;
        MERGE3(m1a, j1a, m2a, j2a, m3a,
               v1[0], i1[0], v2[0], i2[0], v3[0],
               v1[1], i1[1], v2[1], i2[1], v3[1]);
        MERGE3(m1b, j1b, m2b, j2b, m3b,
               v1[2], i1[2], v2[2], i2[2], v3[2],
               v1[3], i1[3], v2[3], i2[3], v3[3]);
        MERGE3(V1, I1, V2, I2, V3,
               m1a, j1a, m2a, j2a, m3a,
               m1b, j1b, m2b, j2b, m3b);
        fin[tid] = I1;
        if (V1 - V2 < TAUS) {
            if (V1 - V3 < TAUS) {            // near-tie: full np rescan
                int slot = atomicAdd(wl_count + 1, 1);
                if (slot < WLCAP) {
                    wlf[slot]  = (h << 16) | (q0 + tid);
                    res[slot]  = ~0ULL;
                    pcnt[slot] = 0;
                }
            } else {                         // provable 2-candidate set
                int slot = atomicAdd(wl_count, 1);
                if (slot < WLCAP) {
                    wl[slot]  = (h << 16) | (q0 + tid);
                    wlc[slot] = (I1 << 16) | I2;
                }
            }
        }
    }
    __syncthreads();

    // ---- gather values[h, fin[q], :] -> out; 32 rows x 16 float4 -----------
#pragma unroll
    for (int k = 0; k < 2; ++k) {
        int f   = tid + k * 256;
        int row = f >> 4;
        int cl  = (f & 15) << 2;
        int idx = fin[row];
        float4 v = *reinterpret_cast<const float4*>(
            values + (size_t)h * CODES * DVI + (size_t)idx * DVI + cl);
        *reinterpret_cast<float4*>(
            out + (size_t)(q0 + row) * DIMX + h * DVI + cl) = v;
    }
}

// ---- pass 2 (fused): 2-cand checks + near-tie partial rescans --------------
// item < cnt0: np-exact 2-candidate duel (lanes 0,1), write out.
// else: (entry e, part 0..7) np-exact scan of 512 codes; packed-key atomicMin;
// fence-ordered completion counter -> last part re-reads min, writes out.
__global__ __launch_bounds__(256) void post_check(const float* __restrict__ x,
                                                  const float* __restrict__ ke,
                                                  const float* __restrict__ e2np,
                                                  const float* __restrict__ values,
                                                  const int* __restrict__ wl_count,
                                                  const int* __restrict__ wl,
                                                  const int* __restrict__ wlc,
                                                  const int* __restrict__ wlf,
                                                  unsigned long long* __restrict__ res,
                                                  int* __restrict__ pcnt,
                                                  float* __restrict__ out) {
    __shared__ float xs[4][DKI];
    const int t = threadIdx.x, w = t >> 6, lane = t & 63;
    int cnt0 = wl_count[0]; if (cnt0 > WLCAP) cnt0 = WLCAP;
    int cnt1 = wl_count[1]; if (cnt1 > WLCAP) cnt1 = WLCAP;
    const int total = cnt0 + cnt1 * 8;

    for (int item = blockIdx.x * 4 + w; item < total; item += gridDim.x * 4) {
        if (item < cnt0) {
            // ---------------- 2-candidate duel ----------------
            int ent = wl[item];
            int h = ent >> 16, nq = ent & 0xffff;
            int cp = wlc[item];
            if (lane < 16) {
                float4 v = *reinterpret_cast<const float4*>(
                    x + (size_t)nq * DIMX + h * DKI + lane * 4);
                *reinterpret_cast<float4*>(&xs[w][lane * 4]) = v;
            }
            asm volatile("s_waitcnt lgkmcnt(0)" ::: "memory");
            __builtin_amdgcn_sched_barrier(0);

            int i1 = (cp >> 16) & 0xffff, i2 = cp & 0xffff;
            float d2 = 0.f;
            if (lane < 2) {
                int myc = lane ? i2 : i1;
                float er[DKI];
                const float4* p = reinterpret_cast<const float4*>(
                    ke + ((size_t)h * CODES + myc) * DKI);
#pragma unroll
                for (int i = 0; i < DKI / 4; ++i) {
                    float4 v = p[i];
                    er[i * 4 + 0] = v.x; er[i * 4 + 1] = v.y;
                    er[i * 4 + 2] = v.z; er[i * 4 + 3] = v.w;
                }
                float x2 = np_sumsq64(xs[w]);
                float dot = np_dot64(xs[w], er);
                {
#pragma clang fp contract(off)
                    d2 = (x2 - 2.0f * dot) + e2np[h * CODES + myc];
                }
            }
            float dA = __shfl(d2, 0, 64);
            float dB = __shfl(d2, 1, 64);
            int win = (dB < dA || (dB == dA && i2 < i1)) ? i2 : i1;
            if (lane < 16) {
                float4 v = *reinterpret_cast<const float4*>(
                    values + ((size_t)h * CODES + win) * DVI + lane * 4);
                *reinterpret_cast<float4*>(
                    out + (size_t)nq * DIMX + h * DVI + lane * 4) = v;
            }
        } else {
            // ---------------- near-tie partial rescan ----------------
            const int j = item - cnt0;
            const int e = j >> 3, part = j & 7;
            const int ent = wlf[e];
            const int h = ent >> 16, nq = ent & 0xffff;
            if (lane < 16) {
                float4 v = *reinterpret_cast<const float4*>(
                    x + (size_t)nq * DIMX + h * DKI + lane * 4);
                *reinterpret_cast<float4*>(&xs[w][lane * 4]) = v;
            }
            asm volatile("s_waitcnt lgkmcnt(0)" ::: "memory");
            __builtin_amdgcn_sched_barrier(0);

            float x2 = np_sumsq64(xs[w]);
            unsigned long long best = ~0ULL;
#pragma unroll 1
            for (int it = 0; it < 8; ++it) {
                int c = part * 512 + it * 64 + lane;
                float er[DKI];
                const float4* p = reinterpret_cast<const float4*>(
                    ke + ((size_t)h * CODES + c) * DKI);
#pragma unroll
                for (int i = 0; i < DKI / 4; ++i) {
                    float4 v = p[i];
                    er[i * 4 + 0] = v.x; er[i * 4 + 1] = v.y;
                    er[i * 4 + 2] = v.z; er[i * 4 + 3] = v.w;
                }
                float dot = np_dot64(xs[w], er);
                float d2;
                {
#pragma clang fp contract(off)
                    d2 = (x2 - 2.0f * dot) + e2np[h * CODES + c];
                }
                unsigned u = __float_as_uint(d2);
                unsigned key = (u & 0x80000000u) ? ~u : (u | 0x80000000u);
                unsigned long long pk =
                    ((unsigned long long)key << 32) | (unsigned)c;
                best = pk < best ? pk : best;
            }
#pragma unroll
            for (int m = 1; m <= 32; m <<= 1) {
                unsigned long long o =
                    (unsigned long long)__shfl_xor((long long)best, m, 64);
                best = o < best ? o : best;
            }
            int lastflag = 0;
            if (lane == 0) {
                atomicMin(res + e, best);
                __threadfence();             // min visible before count
                lastflag = (atomicAdd(pcnt + e, 1) == 7);
            }
            lastflag = __shfl(lastflag, 0, 64);
            if (lastflag) {
                unsigned long long fin = 0;
                if (lane == 0) {
                    __threadfence();         // acquire: see all 8 mins
                    fin = atomicMin(res + e, ~0ULL);   // atomic read
                }
                int win = (int)(__shfl((long long)fin, 0, 64) & 0xFFFFFFFFLL);
                if (lane < 16) {
                    float4 v = *reinterpret_cast<const float4*>(
                        values + ((size_t)h * CODES + win) * DVI + lane * 4);
                    *reinterpret_cast<float4*>(
                        out + (size_t)nq * DIMX + h * DVI + lane * 4) = v;
                }
            }
        }
    }
}

extern "C" void kernel_launch(void* const* d_in, const int* in_sizes, int n_in,
                              void* d_out, int out_size, void* d_ws, size_t ws_size,
                              hipStream_t stream) {
    const float* x      = (const float*)d_in[0];
    // d_in[1] = mask (all ones; unused)
    const float* ke     = (const float*)d_in[2];
    const float* values = (const float*)d_in[3];
    // d_in[4] = key_optim (unused)
    float* out = (float*)d_out;

    char* ws = (char*)d_ws;
    float* e2np          = (float*)ws;          ws += (size_t)HEADS * CODES * 4;      // 196608
    unsigned short* m2bf = (unsigned short*)ws; ws += (size_t)HEADS * 2 * 2048 * 2;   // 98304
    int*   wl_count      = (int*)ws;            ws += 64;
    int*   wl            = (int*)ws;            ws += (size_t)WLCAP * 4;              // 131072
    int*   wlc           = (int*)ws;            ws += (size_t)WLCAP * 4;              // 131072
    int*   wlf           = (int*)ws;            ws += (size_t)WLCAP * 4;              // 131072
    unsigned long long* res = (unsigned long long*)ws; ws += (size_t)WLCAP * 8;       // 262144
    int*   pcnt          = (int*)ws;            ws += (size_t)WLCAP * 4;              // 131072
    char*  EhT           = ws;                  ws += (size_t)HEADS * CODES * 128;    // 6291456

    prep_ke<<<dim3(HEADS * CODES / 32), dim3(256), 0, stream>>>(
        ke, (uint4*)EhT, e2np, m2bf, wl_count);
    dkvb_pass1<<<dim3(1536), dim3(256), 0, stream>>>(
        x, EhT, m2bf, values, wl_count, wl, wlc, wlf, res, pcnt, out);
    post_check<<<dim3(1024), dim3(256), 0, stream>>>(
        x, ke, e2np, values, wl_count, wl, wlc, wlf, res, pcnt, out);
}

// Round 9
// 173.751 us; speedup vs baseline: 1.5084x; 1.1083x over previous
//
#include <hip/hip_runtime.h>

// DiscreteKeyValueBottleneck on MI355X (gfx950)
// B=4 T=1024 H=12 C=4096 DK=DV=64, N=B*T=4096, DIM=768
//
// Round 15 (= r14 resubmit; r14 bench died to container infra, no counters).
// 32x32 tile pinned pass1 at 3 waves/SIMD (live set ~140 VGPR); pushes to
// 4 waves spilled (r6/r7 scratch traffic). Switch to 16x16x32 MFMA:
//  * per-lane state: acc 4, zacc 4, bv*3 = 24 (2 q-tiles x 4), ah 16,
//    staging 2x9 -> ~100 VGPR -> 4 waves/SIMD, launch_bounds(256,4).
//  * wave = 32 q (two 16-row tiles sharing B-frags) x one code quarter,
//    64 chunks of 16 codes; 2 data-MFMA + 1 m2-MFMA per tile per chunk;
//    3-buffer prefetch-2. EhT layout UNCHANGED (16-code chunk = half of
//    a 32-code group, same fragment order: piece=k>>3, cc=c&31).
//  * fragment maps (HW-verified family): A/B row/col=lane&15,
//    k=(lane>>4)*8+j; C col=lane&15, row=(lane>>4)*4+r.
//  * epilogue: 4-step butterfly (lane&15), LDS 4-quarter MERGE3, flag,
//    gather; post_check/prep byte-identical to r13.

#define HEADS 12
#define CODES 4096
#define DKI   64
#define DVI   64
#define DIMX  768
#define TAUS  7.68e-3f    // 64 * 1.2e-4 (scores carry the x64 E-scale)
#define WLCAP 32768

typedef short bf16x8 __attribute__((ext_vector_type(8)));
typedef _Float16 f16x8 __attribute__((ext_vector_type(8)));
typedef float f32x4 __attribute__((ext_vector_type(4)));

__device__ __forceinline__ unsigned short f2bf(float f) {   // RNE
    unsigned int u = __float_as_uint(f);
    return (unsigned short)((u + 0x7fff + ((u >> 16) & 1)) >> 16);
}
__device__ __forceinline__ unsigned short f2h(float f) {    // RNE f32->f16
    _Float16 h = (_Float16)f;
    unsigned short u;
    __builtin_memcpy(&u, &h, 2);
    return u;
}
__device__ __forceinline__ f16x8 as_f16x8(uint4 v) {
    union { uint4 u; f16x8 h; } c; c.u = v; return c.h;
}

// ---------------- numpy bit-exact helpers (fp32, contraction OFF) -----------
__device__ __forceinline__ float np_sumsq64(const float* __restrict__ a) {
#pragma clang fp contract(off)
    float r[8];
#pragma unroll
    for (int j = 0; j < 8; ++j) r[j] = a[j] * a[j];
#pragma unroll
    for (int i = 8; i < 64; i += 8)
#pragma unroll
        for (int j = 0; j < 8; ++j) r[j] += a[i + j] * a[i + j];
    return ((r[0] + r[1]) + (r[2] + r[3])) + ((r[4] + r[5]) + (r[6] + r[7]));
}

__device__ __forceinline__ float np_dot64(const float* __restrict__ xx,
                                          const float* __restrict__ ee) {
#pragma clang fp contract(off)
    float S0 = 0.f, S1 = 0.f, S2 = 0.f, S3 = 0.f;
#pragma unroll
    for (int t = 0; t < 64; t += 16) {
        float p[16];
#pragma unroll
        for (int j = 0; j < 16; ++j) p[j] = xx[t + j] * ee[t + j];
        S0 = p[0] + (p[4] + (p[8]  + (p[12] + S0)));
        S1 = p[1] + (p[5] + (p[9]  + (p[13] + S1)));
        S2 = p[2] + (p[6] + (p[10] + (p[14] + S2)));
        S3 = p[3] + (p[7] + (p[11] + (p[15] + S3)));
    }
    return (S0 + S1) + (S2 + S3);
}

// ---- prep: np-exact e2; Eh(fp16,x64) fragment layout; m2bf(-32*e2) ---------
// Block = 32 codes, 8 threads/code (t: piece p=t>>5, code cw=t&31).
// uint4 units: [((pair*64+gg)*8 + piece)*32 + cc], pair=h*2+half, gg=(c&2047)>>5.
__global__ __launch_bounds__(256) void prep_ke(const float* __restrict__ ke,
                                               uint4* __restrict__ EhT,
                                               float* __restrict__ e2np,
                                               unsigned short* __restrict__ m2bf,
                                               int* __restrict__ wl_count) {
    __shared__ float sq[32][64];
    __shared__ float rr[32][8];
    const int t = threadIdx.x;
    if (blockIdx.x == 0 && t < 2) wl_count[t] = 0;
    const int p = t >> 5, cw = t & 31;
    const int idx = blockIdx.x * 32 + cw;          // all 32 codes share h/half/gg

    float er[8];
    {
        const float4* p4 = reinterpret_cast<const float4*>(
            ke + (size_t)idx * DKI + p * 8);
        float4 v0 = p4[0], v1 = p4[1];
        er[0] = v0.x; er[1] = v0.y; er[2] = v0.z; er[3] = v0.w;
        er[4] = v1.x; er[5] = v1.y; er[6] = v1.z; er[7] = v1.w;
    }
    {
#pragma clang fp contract(off)
#pragma unroll
        for (int j = 0; j < 8; ++j) sq[cw][p * 8 + j] = er[j] * er[j];
    }
    __syncthreads();
    {   // residue chain rho = p : r = ((sq[rho]+sq[8+rho])+sq[16+rho])+...
#pragma clang fp contract(off)
        float r = sq[cw][p];
#pragma unroll
        for (int k = 1; k < 8; ++k) r = r + sq[cw][k * 8 + p];
        rr[cw][p] = r;
    }
    __syncthreads();
    const int h = idx >> 12, c = idx & 4095;
    const int half = c >> 11, gg = (c & 2047) >> 5;
    const int pair = h * 2 + half;
    if (p == 0) {
#pragma clang fp contract(off)
        float e2 = ((rr[cw][0] + rr[cw][1]) + (rr[cw][2] + rr[cw][3])) +
                   ((rr[cw][4] + rr[cw][5]) + (rr[cw][6] + rr[cw][7]));
        e2np[idx] = e2;
        m2bf[(size_t)pair * 2048 + (c & 2047)] = f2bf(-32.f * e2);
    }

    unsigned int hb[8];
#pragma unroll
    for (int j = 0; j < 8; ++j)
        hb[j] = f2h(er[j] * 64.f);                 // exact pow2 scale
    uint4 hv;
    hv.x = hb[0] | (hb[1] << 16); hv.y = hb[2] | (hb[3] << 16);
    hv.z = hb[4] | (hb[5] << 16); hv.w = hb[6] | (hb[7] << 16);
    EhT[((size_t)(pair * 64 + gg) * 8 + p) * 32 + cw] = hv;
}

// sorted-triple merge network (tie -> first/left operand)
#define MERGE3(v1o, i1o, v2o, i2o, v3o,                                   \
               a1, j1, a2, j2, a3, b1, k1, b2, k2, b3)                    \
    {                                                                     \
        bool t1 = (b1) > (a1);                                            \
        float _l1 = t1 ? (a1) : (b1);  int _k1 = t1 ? (j1) : (k1);        \
        (v1o) = t1 ? (b1) : (a1);      (i1o) = t1 ? (k1) : (j1);          \
        float _s2 = t1 ? (b2) : (a2);  int _u2 = t1 ? (k2) : (j2);        \
        bool t2 = _s2 > _l1;                                              \
        (v2o) = t2 ? _s2 : _l1;        (i2o) = t2 ? _u2 : _k1;            \
        float _l2 = t2 ? _l1 : _s2;                                       \
        float _s3 = t2 ? (t1 ? (b3) : (a3)) : (t1 ? (a2) : (b2));         \
        bool t3 = _s3 > _l2;                                              \
        (v3o) = t3 ? _s3 : _l2;                                           \
    }

// ---- pass 1: 16x16x32 MFMA, low-VGPR, 32q x quarter waves ------------------
// grid 1536 = 12 heads x 128 q-blocks (h=b%12). Block: 4 waves, 32 queries,
// full codebook; wave w covers codes [w*1024,(w+1)*1024) in 64 chunks of 16.
// Per wave: two 16-row q-tiles share the B fragments.
__global__ __launch_bounds__(256, 4) void dkvb_pass1(
        const float* __restrict__ x,
        const char* __restrict__ EhT,
        const unsigned short* __restrict__ m2bf,
        const float* __restrict__ values,
        int* __restrict__ wl_count,
        int* __restrict__ wl,
        int* __restrict__ wlc,
        int* __restrict__ wlf,
        unsigned long long* __restrict__ res,
        int* __restrict__ pcnt,
        float* __restrict__ out) {
    __shared__ float sb1[4][32], sb2[4][32], sb3[4][32];
    __shared__ int   sbi[4][32];
    __shared__ int   fin[32];

    const int tid  = threadIdx.x;
    const int h    = blockIdx.x % 12;
    const int qb   = blockIdx.x / 12;
    const int w    = tid >> 6;               // code quarter
    const int lane = tid & 63;
    const int cl16 = lane & 15;              // B col (code) / A row (query)
    const int kg   = lane >> 4;              // k-group (k = kg*8+j within K=32)
    const int q0   = qb * 32;
    const int pair = h * 2 + (w >> 1);
    const int qoff = (w >> 1) * 2048 + (w & 1) * 1024;   // quarter code base

    // ---- A fragments (fp16): tile T rows q0+T*16+cl16; k = t*32 + kg*8 + j
    f16x8 ah[2][2];
#pragma unroll
    for (int T = 0; T < 2; ++T) {
        const float* xrow = x + (size_t)(q0 + T * 16 + cl16) * DIMX + h * DKI;
#pragma unroll
        for (int t = 0; t < 2; ++t) {
            const float* p = xrow + t * 32 + kg * 8;
            float4 v0 = *reinterpret_cast<const float4*>(p);
            float4 v1 = *reinterpret_cast<const float4*>(p + 4);
            f16x8 hv;
            hv[0] = (_Float16)v0.x; hv[1] = (_Float16)v0.y;
            hv[2] = (_Float16)v0.z; hv[3] = (_Float16)v0.w;
            hv[4] = (_Float16)v1.x; hv[5] = (_Float16)v1.y;
            hv[6] = (_Float16)v1.z; hv[7] = (_Float16)v1.w;
            ah[T][t] = hv;
        }
    }
    // m2 A-side const fragment: k=0 slot = 1.0bf16 (kg==0 lanes only)
    const bf16x8 am2 = (bf16x8){(short)(kg ? 0 : 0x3F80), 0, 0, 0, 0, 0, 0, 0};

    // B base: unit (pair*64 + (w&1)*32 quarter-groups), piece kg, code cl16
    const char* gE = EhT + (size_t)(pair * 64 + (w & 1) * 32) * 4096
                   + (size_t)kg * 512 + (size_t)cl16 * 16;
    const unsigned short* gm = m2bf + (size_t)pair * 2048
                             + (size_t)(w & 1) * 1024 + cl16;

    f32x4 zacc;
#pragma unroll
    for (int r = 0; r < 4; ++r) zacc[r] = 0.f;

    float bv[2][4], bv2[2][4], bv3[2][4];
#pragma unroll
    for (int T = 0; T < 2; ++T)
#pragma unroll
        for (int r = 0; r < 4; ++r) {
            bv[T][r] = -1e30f; bv2[T][r] = -1e30f; bv3[T][r] = -1e30f;
        }

    auto LOADF = [&](int i, uint4& b0, uint4& b1, unsigned short& mA) {
        const char* p = gE + (size_t)(i >> 1) * 4096 + (size_t)(i & 1) * 256;
        b0 = *reinterpret_cast<const uint4*>(p);          // t=0 (k 0..31)
        b1 = *reinterpret_cast<const uint4*>(p + 2048);   // t=1 (k 32..63)
        mA = gm[i * 16];
    };
    auto COMPUTE = [&](int i, uint4 b0, uint4 b1, unsigned short mA) {
        bf16x8 bm = (bf16x8){(short)(kg ? 0 : mA), 0, 0, 0, 0, 0, 0, 0};
        unsigned enc = (unsigned)i;          // 6-bit chunk id in mantissa LSBs
#pragma unroll
        for (int T = 0; T < 2; ++T) {
            f32x4 acc;
            acc = __builtin_amdgcn_mfma_f32_16x16x32_bf16(am2, bm, zacc, 0, 0, 0);
            acc = __builtin_amdgcn_mfma_f32_16x16x32_f16(ah[T][0], as_f16x8(b0),
                                                         acc, 0, 0, 0);
            acc = __builtin_amdgcn_mfma_f32_16x16x32_f16(ah[T][1], as_f16x8(b1),
                                                         acc, 0, 0, 0);
#pragma unroll
            for (int r = 0; r < 4; ++r) {
                float sp = __uint_as_float(
                    (__float_as_uint(acc[r]) & 0xFFFFFFC0u) | enc);
                bv3[T][r] = __builtin_amdgcn_fmed3f(bv3[T][r], sp, bv2[T][r]);
                bv2[T][r] = __builtin_amdgcn_fmed3f(bv2[T][r], sp, bv[T][r]);
                bv[T][r]  = fmaxf(bv[T][r], sp);
            }
        }
    };

    // 3-buffer rotation, prefetch distance 2, static names, no guards
    uint4 A0, A1, B0, B1, C0, C1;
    unsigned short Am, Bm, Cm;
    LOADF(0, A0, A1, Am);
    LOADF(1, B0, B1, Bm);
#pragma unroll 1
    for (int i = 0; i < 60; i += 3) {
        LOADF(i + 2, C0, C1, Cm);
        COMPUTE(i, A0, A1, Am);
        LOADF(i + 3, A0, A1, Am);
        COMPUTE(i + 1, B0, B1, Bm);
        LOADF(i + 4, B0, B1, Bm);
        COMPUTE(i + 2, C0, C1, Cm);
    }
    LOADF(62, C0, C1, Cm);
    COMPUTE(60, A0, A1, Am);
    LOADF(63, A0, A1, Am);
    COMPUTE(61, B0, B1, Bm);
    COMPUTE(62, C0, C1, Cm);
    COMPUTE(63, A0, A1, Am);

    // ---- decode packed indices (head-global), 4-step cross-col butterfly ---
    int bi1[2][4], bi2[2][4];
#pragma unroll
    for (int T = 0; T < 2; ++T)
#pragma unroll
        for (int r = 0; r < 4; ++r) {
            bi1[T][r] = (int)(__float_as_uint(bv[T][r])  & 63u) * 16 + cl16 + qoff;
            bi2[T][r] = (int)(__float_as_uint(bv2[T][r]) & 63u) * 16 + cl16 + qoff;
        }
#pragma unroll
    for (int T = 0; T < 2; ++T)
#pragma unroll
        for (int r = 0; r < 4; ++r) {
#pragma unroll
            for (int m = 1; m <= 8; m <<= 1) {
                float p1 = __shfl_xor(bv[T][r],  m, 64);
                float p2 = __shfl_xor(bv2[T][r], m, 64);
                float p3 = __shfl_xor(bv3[T][r], m, 64);
                int   q1 = __shfl_xor(bi1[T][r], m, 64);
                int   q2 = __shfl_xor(bi2[T][r], m, 64);
                bool t1 = (p1 > bv[T][r]) || (p1 == bv[T][r] && q1 < bi1[T][r]);
                float w1 = t1 ? p1 : bv[T][r];   int j1 = t1 ? q1 : bi1[T][r];
                float l1 = t1 ? bv[T][r] : p1;   int k1 = t1 ? bi1[T][r] : q1;
                float s2 = t1 ? p2 : bv2[T][r];  int u2 = t1 ? q2 : bi2[T][r];
                bool t2 = s2 > l1;
                float w2 = t2 ? s2 : l1;         int j2 = t2 ? u2 : k1;
                float l2 = t2 ? l1 : s2;
                float s3 = t2 ? (t1 ? p3 : bv3[T][r]) : (t1 ? bv2[T][r] : p2);
                bool t3 = s3 > l2;
                float w3 = t3 ? s3 : l2;
                bv[T][r] = w1; bi1[T][r] = j1;
                bv2[T][r] = w2; bi2[T][r] = j2;
                bv3[T][r] = w3;
            }
        }
    if (cl16 == 0) {                         // lanes 0,16,32,48: rows kg*4+r
#pragma unroll
        for (int T = 0; T < 2; ++T)
#pragma unroll
            for (int r = 0; r < 4; ++r) {
                int row = T * 16 + kg * 4 + r;           // 0..31
                sb1[w][row] = bv[T][r];
                sb2[w][row] = bv2[T][r];
                sb3[w][row] = bv3[T][r];
                sbi[w][row] = (bi1[T][r] << 16) | bi2[T][r];
            }
    }
    __syncthreads();

    // ---- 4-way quarter merge, flag, route worklists ------------------------
    if (tid < 32) {
        float v1[4], v2[4], v3[4]; int i1[4], i2[4];
#pragma unroll
        for (int qd = 0; qd < 4; ++qd) {
            v1[qd] = sb1[qd][tid]; v2[qd] = sb2[qd][tid]; v3[qd] = sb3[qd][tid];
            int pk = sbi[qd][tid];
            i1[qd] = (pk >> 16) & 0xffff; i2[qd] = pk & 0xffff;
        }
        float m1a, m2a, m3a, m1b, m2b, m3b, V1, V2, V3;
        int j1a, j2a, j1b, j2b, I1, I2;
        MERGE3(m1a, j1a, m2a, j2a, m3a,
               v1[0], i1[0], v2[0], i2[0], v3[0],
               v1[1], i1[1], v2[1], i2[1], v3[1]);
        MERGE3(m1b, j1b, m2b, j2b, m3b,
               v1[2], i1[2], v2[2], i2[2], v3[2],
               v1[3], i1[3], v2[3], i2[3], v3[3]);
        MERGE3(V1, I1, V2, I2, V3,
               m1a, j1a, m2a, j2a, m3a,
               m1b, j1b, m2b, j2b, m3b);
        fin[tid] = I1;
        if (V1 - V2 < TAUS) {
            if (V1 - V3 < TAUS) {            // near-tie: full np rescan
                int slot = atomicAdd(wl_count + 1, 1);
                if (slot < WLCAP) {
                    wlf[slot]  = (h << 16) | (q0 + tid);
                    res[slot]  = ~0ULL;
                    pcnt[slot] = 0;
                }
            } else {                         // provable 2-candidate set
                int slot = atomicAdd(wl_count, 1);
                if (slot < WLCAP) {
                    wl[slot]  = (h << 16) | (q0 + tid);
                    wlc[slot] = (I1 << 16) | I2;
                }
            }
        }
    }
    __syncthreads();

    // ---- gather values[h, fin[q], :] -> out; 32 rows x 16 float4 -----------
#pragma unroll
    for (int k = 0; k < 2; ++k) {
        int f   = tid + k * 256;
        int row = f >> 4;
        int cl  = (f & 15) << 2;
        int idx = fin[row];
        float4 v = *reinterpret_cast<const float4*>(
            values + (size_t)h * CODES * DVI + (size_t)idx * DVI + cl);
        *reinterpret_cast<float4*>(
            out + (size_t)(q0 + row) * DIMX + h * DVI + cl) = v;
    }
}

// ---- pass 2 (fused): 2-cand checks + near-tie partial rescans --------------
// item < cnt0: np-exact 2-candidate duel (lanes 0,1), write out.
// else: (entry e, part 0..7) np-exact scan of 512 codes; packed-key atomicMin;
// fence-ordered completion counter -> last part re-reads min, writes out.
__global__ __launch_bounds__(256) void post_check(const float* __restrict__ x,
                                                  const float* __restrict__ ke,
                                                  const float* __restrict__ e2np,
                                                  const float* __restrict__ values,
                                                  const int* __restrict__ wl_count,
                                                  const int* __restrict__ wl,
                                                  const int* __restrict__ wlc,
                                                  const int* __restrict__ wlf,
                                                  unsigned long long* __restrict__ res,
                                                  int* __restrict__ pcnt,
                                                  float* __restrict__ out) {
    __shared__ float xs[4][DKI];
    const int t = threadIdx.x, w = t >> 6, lane = t & 63;
    int cnt0 = wl_count[0]; if (cnt0 > WLCAP) cnt0 = WLCAP;
    int cnt1 = wl_count[1]; if (cnt1 > WLCAP) cnt1 = WLCAP;
    const int total = cnt0 + cnt1 * 8;

    for (int item = blockIdx.x * 4 + w; item < total; item += gridDim.x * 4) {
        if (item < cnt0) {
            // ---------------- 2-candidate duel ----------------
            int ent = wl[item];
            int h = ent >> 16, nq = ent & 0xffff;
            int cp = wlc[item];
            if (lane < 16) {
                float4 v = *reinterpret_cast<const float4*>(
                    x + (size_t)nq * DIMX + h * DKI + lane * 4);
                *reinterpret_cast<float4*>(&xs[w][lane * 4]) = v;
            }
            asm volatile("s_waitcnt lgkmcnt(0)" ::: "memory");
            __builtin_amdgcn_sched_barrier(0);

            int i1 = (cp >> 16) & 0xffff, i2 = cp & 0xffff;
            float d2 = 0.f;
            if (lane < 2) {
                int myc = lane ? i2 : i1;
                float er[DKI];
                const float4* p = reinterpret_cast<const float4*>(
                    ke + ((size_t)h * CODES + myc) * DKI);
#pragma unroll
                for (int i = 0; i < DKI / 4; ++i) {
                    float4 v = p[i];
                    er[i * 4 + 0] = v.x; er[i * 4 + 1] = v.y;
                    er[i * 4 + 2] = v.z; er[i * 4 + 3] = v.w;
                }
                float x2 = np_sumsq64(xs[w]);
                float dot = np_dot64(xs[w], er);
                {
#pragma clang fp contract(off)
                    d2 = (x2 - 2.0f * dot) + e2np[h * CODES + myc];
                }
            }
            float dA = __shfl(d2, 0, 64);
            float dB = __shfl(d2, 1, 64);
            int win = (dB < dA || (dB == dA && i2 < i1)) ? i2 : i1;
            if (lane < 16) {
                float4 v = *reinterpret_cast<const float4*>(
                    values + ((size_t)h * CODES + win) * DVI + lane * 4);
                *reinterpret_cast<float4*>(
                    out + (size_t)nq * DIMX + h * DVI + lane * 4) = v;
            }
        } else {
            // ---------------- near-tie partial rescan ----------------
            const int j = item - cnt0;
            const int e = j >> 3, part = j & 7;
            const int ent = wlf[e];
            const int h = ent >> 16, nq = ent & 0xffff;
            if (lane < 16) {
                float4 v = *reinterpret_cast<const float4*>(
                    x + (size_t)nq * DIMX + h * DKI + lane * 4);
                *reinterpret_cast<float4*>(&xs[w][lane * 4]) = v;
            }
            asm volatile("s_waitcnt lgkmcnt(0)" ::: "memory");
            __builtin_amdgcn_sched_barrier(0);

            float x2 = np_sumsq64(xs[w]);
            unsigned long long best = ~0ULL;
#pragma unroll 1
            for (int it = 0; it < 8; ++it) {
                int c = part * 512 + it * 64 + lane;
                float er[DKI];
                const float4* p = reinterpret_cast<const float4*>(
                    ke + ((size_t)h * CODES + c) * DKI);
#pragma unroll
                for (int i = 0; i < DKI / 4; ++i) {
                    float4 v = p[i];
                    er[i * 4 + 0] = v.x; er[i * 4 + 1] = v.y;
                    er[i * 4 + 2] = v.z; er[i * 4 + 3] = v.w;
                }
                float dot = np_dot64(xs[w], er);
                float d2;
                {
#pragma clang fp contract(off)
                    d2 = (x2 - 2.0f * dot) + e2np[h * CODES + c];
                }
                unsigned u = __float_as_uint(d2);
                unsigned key = (u & 0x80000000u) ? ~u : (u | 0x80000000u);
                unsigned long long pk =
                    ((unsigned long long)key << 32) | (unsigned)c;
                best = pk < best ? pk : best;
            }
#pragma unroll
            for (int m = 1; m <= 32; m <<= 1) {
                unsigned long long o =
                    (unsigned long long)__shfl_xor((long long)best, m, 64);
                best = o < best ? o : best;
            }
            int lastflag = 0;
            if (lane == 0) {
                atomicMin(res + e, best);
                __threadfence();             // min visible before count
                lastflag = (atomicAdd(pcnt + e, 1) == 7);
            }
            lastflag = __shfl(lastflag, 0, 64);
            if (lastflag) {
                unsigned long long fin = 0;
                if (lane == 0) {
                    __threadfence();         // acquire: see all 8 mins
                    fin = atomicMin(res + e, ~0ULL);   // atomic read
                }
                int win = (int)(__shfl((long long)fin, 0, 64) & 0xFFFFFFFFLL);
                if (lane < 16) {
                    float4 v = *reinterpret_cast<const float4*>(
                        values + ((size_t)h * CODES + win) * DVI + lane * 4);
                    *reinterpret_cast<float4*>(
                        out + (size_t)nq * DIMX + h * DVI + lane * 4) = v;
                }
            }
        }
    }
}

extern "C" void kernel_launch(void* const* d_in, const int* in_sizes, int n_in,
                              void* d_out, int out_size, void* d_ws, size_t ws_size,
                              hipStream_t stream) {
    const float* x      = (const float*)d_in[0];
    // d_in[1] = mask (all ones; unused)
    const float* ke     = (const float*)d_in[2];
    const float* values = (const float*)d_in[3];
    // d_in[4] = key_optim (unused)
    float* out = (float*)d_out;

    char* ws = (char*)d_ws;
    float* e2np          = (float*)ws;          ws += (size_t)HEADS * CODES * 4;      // 196608
    unsigned short* m2bf = (unsigned short*)ws; ws += (size_t)HEADS * 2 * 2048 * 2;   // 98304
    int*   wl_count      = (int*)ws;            ws += 64;
    int*   wl            = (int*)ws;            ws += (size_t)WLCAP * 4;              // 131072
    int*   wlc           = (int*)ws;            ws += (size_t)WLCAP * 4;              // 131072
    int*   wlf           = (int*)ws;            ws += (size_t)WLCAP * 4;              // 131072
    unsigned long long* res = (unsigned long long*)ws; ws += (size_t)WLCAP * 8;       // 262144
    int*   pcnt          = (int*)ws;            ws += (size_t)WLCAP * 4;              // 131072
    char*  EhT           = ws;                  ws += (size_t)HEADS * CODES * 128;    // 6291456

    prep_ke<<<dim3(HEADS * CODES / 32), dim3(256), 0, stream>>>(
        ke, (uint4*)EhT, e2np, m2bf, wl_count);
    dkvb_pass1<<<dim3(1536), dim3(256), 0, stream>>>(
        x, EhT, m2bf, values, wl_count, wl, wlc, wlf, res, pcnt, out);
    post_check<<<dim3(1024), dim3(256), 0, stream>>>(
        x, ke, e2np, values, wl_count, wl, wlc, wlf, res, pcnt, out);
}